// Round 5
// baseline (662.212 us; speedup 1.0000x reference)
//
#include <hip/hip_runtime.h>

// ---------------------------------------------------------------------------
// D=256 HEADS=8 DH=32 LEVELS=4 POINTS=4 DFFN=1024 B=8 NQ=300 NC=16
// M1 = 38400, LEN_IN = 5440, value rows = 43520
// SPATIAL = (64,64),(32,32),(16,16),(8,8); level starts 0,4096,5120,5376
// ---------------------------------------------------------------------------

typedef __bf16 bf16x8 __attribute__((ext_vector_type(8)));
typedef float  f32x4  __attribute__((ext_vector_type(4)));
typedef float  f32x2  __attribute__((ext_vector_type(2)));

__device__ __forceinline__ unsigned pk_bf16(float lo, float hi)
{
    unsigned a = __float_as_uint(lo) + 0x8000u;
    unsigned b = __float_as_uint(hi) + 0x8000u;
    return __builtin_amdgcn_perm(b, a, 0x07060302u);
}
__device__ __forceinline__ unsigned short f2bf(float v)
{
    return (unsigned short)((__float_as_uint(v) + 0x8000u) >> 16);
}
__device__ __forceinline__ float bf_lo(unsigned u) { return __uint_as_float(u << 16); }
__device__ __forceinline__ float bf_hi(unsigned u) { return __uint_as_float(u & 0xffff0000u); }
__device__ __forceinline__ float bf1(unsigned short u) { return __uint_as_float((unsigned)u << 16); }
__device__ __forceinline__ f32x2 bfpair(unsigned u)
{
    f32x2 r;
    r.x = __uint_as_float(u << 16);
    r.y = __uint_as_float(u & 0xffff0000u);
    return r;
}

// XCD-aware chunked block swizzle (bijective for any nwg; m204 variant).
__device__ __forceinline__ int xcd_swz(int wgid, int nwg)
{
    const int q = nwg >> 3, r = nwg & 7;
    const int x = wgid & 7, k = wgid >> 3;
    return (x < r ? x * (q + 1) : r * (q + 1) + (x - r) * q) + k;
}

// async global->LDS, 16 B per lane. LDS dest must be wave-uniform base + lane*16.
__device__ __forceinline__ void gl_lds16(const unsigned short* g, unsigned short* l)
{
    __builtin_amdgcn_global_load_lds(
        (const __attribute__((address_space(1))) unsigned int*)g,
        (__attribute__((address_space(3))) unsigned int*)l,
        16, 0, 0);
}

// ---------------------------------------------------------------------------
// Weight pre-conversion fp32 -> bf16 (8 segments, one dispatch).
// ---------------------------------------------------------------------------
struct WcvtArgs {
    const float* src[8];
    unsigned short* dst[8];
    int n4[8];
};

__global__ __launch_bounds__(256) void wcvt(WcvtArgs a)
{
    const int gid = blockIdx.x * 256 + threadIdx.x;
    const int stride = gridDim.x * 256;
#pragma unroll
    for (int s = 0; s < 8; s++) {
        const float4* sp = (const float4*)a.src[s];
        uint2* dp = (uint2*)a.dst[s];
        for (int i = gid; i < a.n4[s]; i += stride) {
            float4 f = sp[i];
            uint2 o; o.x = pk_bf16(f.x, f.y); o.y = pk_bf16(f.z, f.w);
            dp[i] = o;
        }
    }
}

// ---------------------------------------------------------------------------
// Activation pre-conversion: tgtB = bf16(tgt), qB = bf16(tgt+qpos),
// srcB = bf16(src).
// ---------------------------------------------------------------------------
__global__ __launch_bounds__(256) void cvt_acts(
    const float* __restrict__ tgt, const float* __restrict__ qpos,
    const float* __restrict__ src,
    unsigned short* __restrict__ tgtB, unsigned short* __restrict__ qB,
    unsigned short* __restrict__ srcB)
{
    const int gid = blockIdx.x * 256 + threadIdx.x;
    const int stride = gridDim.x * 256;
    for (int i = gid; i < 2457600; i += stride) {          // 38400*256/4
        float4 t = ((const float4*)tgt)[i];
        float4 p = ((const float4*)qpos)[i];
        uint2 a; a.x = pk_bf16(t.x, t.y); a.y = pk_bf16(t.z, t.w);
        ((uint2*)tgtB)[i] = a;
        uint2 b; b.x = pk_bf16(t.x + p.x, t.y + p.y);
        b.y = pk_bf16(t.z + p.z, t.w + p.w);
        ((uint2*)qB)[i] = b;
    }
    for (int i = gid; i < 2785280; i += stride) {          // 8*5440*256/4
        float4 s = ((const float4*)src)[i];
        uint2 c; c.x = pk_bf16(s.x, s.y); c.y = pk_bf16(s.z, s.w);
        ((uint2*)srcB)[i] = c;
    }
}

// ---------------------------------------------------------------------------
// GEMM core (m97 structure): 128x128 tile, BK=32, double-buffered LDS,
// global_load_lds width=16 staging, one barrier per K-step. 4 waves (2x2).
// Both-sides XOR slot-swizzle (slot ^= (row>>1)&3).
// ---------------------------------------------------------------------------
__device__ __forceinline__ void gemm_core128(
    const unsigned short* __restrict__ Ab,
    const unsigned short* __restrict__ Wb, const float* __restrict__ bias,
    void* __restrict__ Cv, int outbf16, int relu,
    int row0, int col0, int N, int K,
    unsigned short (*sA)[128][32], unsigned short (*sB)[128][32])
{
    const int tid  = threadIdx.x;
    const int lane = tid & 63;
    const int wv   = tid >> 6;
    const int wr   = wv >> 1;
    const int wc   = wv & 1;
    const int lm   = lane & 15;
    const int q    = lane >> 4;
    const int q4   = q << 2;

    const int tr = tid >> 2;
    const int ts = tid & 3;

    f32x4 acc[4][4] = {};
    const int iters = K >> 5;

    auto stage = [&](int buf, int k) {
#pragma unroll
        for (int r = 0; r < 2; ++r) {
            const int row = r * 64 + tr;
            const int sw  = ts ^ ((row >> 1) & 3);
            gl_lds16(Ab + (size_t)(row0 + row) * K + k + sw * 8,
                     &sA[buf][0][0] + (size_t)(r * 256 + tid) * 8);
            gl_lds16(Wb + (size_t)(col0 + row) * K + k + sw * 8,
                     &sB[buf][0][0] + (size_t)(r * 256 + tid) * 8);
        }
    };

    stage(0, 0);

    for (int it = 0; it < iters; ++it) {
        __syncthreads();
        const int buf = it & 1;
        if (it + 1 < iters) stage(buf ^ 1, (it + 1) << 5);

        bf16x8 av[4], bv[4];
#pragma unroll
        for (int mi = 0; mi < 4; mi++) {
            const int row = wr * 64 + mi * 16 + lm;
            av[mi] = *(const bf16x8*)&sA[buf][row][(q ^ ((row >> 1) & 3)) * 8];
        }
#pragma unroll
        for (int ni = 0; ni < 4; ni++) {
            const int row = wc * 64 + ni * 16 + lm;
            bv[ni] = *(const bf16x8*)&sB[buf][row][(q ^ ((row >> 1) & 3)) * 8];
        }
#pragma unroll
        for (int mi = 0; mi < 4; mi++)
#pragma unroll
            for (int ni = 0; ni < 4; ni++)
                acc[mi][ni] = __builtin_amdgcn_mfma_f32_16x16x32_bf16(
                    av[mi], bv[ni], acc[mi][ni], 0, 0, 0);
    }

#pragma unroll
    for (int ni = 0; ni < 4; ni++) {
        const int col = col0 + wc * 64 + ni * 16 + lm;
        const float bsv = bias[col];
#pragma unroll
        for (int mi = 0; mi < 4; mi++) {
            const int rowb = row0 + wr * 64 + mi * 16 + q4;
#pragma unroll
            for (int rr = 0; rr < 4; rr++) {
                float v = acc[mi][ni][rr] + bsv;
                if (relu) v = fmaxf(v, 0.f);
                if (outbf16)
                    ((unsigned short*)Cv)[(size_t)(rowb + rr) * N + col] = f2bf(v);
                else
                    ((float*)Cv)[(size_t)(rowb + rr) * N + col] = v;
            }
        }
    }
}

__global__ __launch_bounds__(256) void gemm_std128(
    const unsigned short* __restrict__ Ab,
    const unsigned short* __restrict__ Wb, const float* __restrict__ bias,
    void* __restrict__ Cv, int outbf16, int relu, int N, int K)
{
    __shared__ unsigned short sA[2][128][32];
    __shared__ unsigned short sB[2][128][32];
    const int nwg = gridDim.x * gridDim.y;
    const int w = xcd_swz(blockIdx.x + gridDim.x * blockIdx.y, nwg);
    const int x = w % gridDim.x, y = w / gridDim.x;
    gemm_core128(Ab, Wb, bias, Cv, outbf16, relu,
                 y * 128, x * 128, N, K, sA, sB);
}

// fused: qk = qB@Wqk^T (N=512, x=0..3), v = tgtB@Wv^T (x=4..5),
// value = srcB@Wval^T over 43520 rows (x=6..7). grid (8, 340).
__global__ __launch_bounds__(256) void gemm_qkvval(
    const unsigned short* __restrict__ qB, const unsigned short* __restrict__ tgtB,
    const unsigned short* __restrict__ srcB,
    const unsigned short* __restrict__ Wsa, const float* __restrict__ bsa,
    unsigned short* __restrict__ qkB, unsigned short* __restrict__ vB,
    const unsigned short* __restrict__ Wval, const float* __restrict__ bval,
    unsigned short* __restrict__ valB)
{
    __shared__ unsigned short sA[2][128][32];
    __shared__ unsigned short sB[2][128][32];
    const int w = xcd_swz(blockIdx.x + 8 * blockIdx.y, 2720);
    const int x = w & 7, y = w >> 3;
    if (x < 4) {
        if (y >= 300) return;
        gemm_core128(qB, Wsa, bsa, qkB, 1, 0, y * 128, x * 128, 512, 256, sA, sB);
    } else if (x < 6) {
        if (y >= 300) return;
        gemm_core128(tgtB, Wsa + 512 * 256, bsa + 512, vB, 1, 0,
                     y * 128, (x - 4) * 128, 256, 256, sA, sB);
    } else {
        gemm_core128(srcB, Wval, bval, valB, 1, 0,
                     y * 128, (x - 6) * 128, 256, 256, sA, sB);
    }
}

// fused: off (N=256, x=0..1, bf16 out) and attw logits (N=128, x=2, fp32 out)
__global__ __launch_bounds__(256) void gemm_offaw(
    const unsigned short* __restrict__ X,
    const unsigned short* __restrict__ Woff, const float* __restrict__ boff,
    unsigned short* __restrict__ offB,
    const unsigned short* __restrict__ Watt, const float* __restrict__ batt,
    float* __restrict__ awL)
{
    __shared__ unsigned short sA[2][128][32];
    __shared__ unsigned short sB[2][128][32];
    const int w = xcd_swz(blockIdx.x + 3 * blockIdx.y, 900);
    const int x = w % 3, y = w / 3;
    if (x >= 2)
        gemm_core128(X, Watt, batt, awL, 0, 0,
                     y * 128, 0, 128, 256, sA, sB);
    else
        gemm_core128(X, Woff, boff, offB, 1, 0,
                     y * 128, x * 128, 256, 256, sA, sB);
}

// ---------------------------------------------------------------------------
// GEMM (N=256 full row) + residual + LayerNorm fused. 64x256 tile, 256 thr,
// 4 waves each 64x64 (wave col wc). Epilogue: v = C + bias + R; row LN via
// 16-lane shfl partial + cross-wave LDS reduce; write f32 out and optional
// bf16 out2 (+qpos). Replaces gemm_std128 + ln_res4 pairs.
// ---------------------------------------------------------------------------
template <int WRITE2, int ADDQ>
__global__ __launch_bounds__(256) void gemm_ln64(
    const unsigned short* __restrict__ Ab,   // [M,K] bf16
    const unsigned short* __restrict__ Wb,   // [256,K] bf16
    const float* __restrict__ bias,          // [256]
    const float* __restrict__ R,             // [M,256] f32 residual
    const float* __restrict__ lnw, const float* __restrict__ lnb,
    float* __restrict__ outF,                // [M,256] f32
    unsigned short* __restrict__ out2,       // [M,256] bf16
    const float* __restrict__ qpos,
    int K, int nblk)
{
    __shared__ unsigned short sA[2][64][32];
    __shared__ unsigned short sB[2][256][32];
    __shared__ float red[64][10];   // [0..3] sum, [4..7] sumsq, [8] mean, [9] rstd

    const int wblk = xcd_swz(blockIdx.x, nblk);
    const int row0 = wblk * 64;

    const int tid  = threadIdx.x;
    const int lane = tid & 63;
    const int wc   = tid >> 6;         // wave col 0..3 (64 cols each)
    const int lm   = lane & 15;
    const int q    = lane >> 4;
    const int q4   = q << 2;

    const int tr = tid >> 2;           // 0..63
    const int ts = tid & 3;

    f32x4 acc[4][4] = {};
    const int iters = K >> 5;

    auto stage = [&](int buf, int k) {
        {
            const int row = tr;
            const int sw  = ts ^ ((row >> 1) & 3);
            gl_lds16(Ab + (size_t)(row0 + row) * K + k + sw * 8,
                     &sA[buf][0][0] + (size_t)tid * 8);
        }
#pragma unroll
        for (int r = 0; r < 4; ++r) {
            const int row = r * 64 + tr;
            const int sw  = ts ^ ((row >> 1) & 3);
            gl_lds16(Wb + (size_t)row * K + k + sw * 8,
                     &sB[buf][0][0] + (size_t)(r * 256 + tid) * 8);
        }
    };

    stage(0, 0);

    for (int it = 0; it < iters; ++it) {
        __syncthreads();
        const int buf = it & 1;
        if (it + 1 < iters) stage(buf ^ 1, (it + 1) << 5);

        bf16x8 av[4], bv[4];
#pragma unroll
        for (int mi = 0; mi < 4; mi++) {
            const int row = mi * 16 + lm;
            av[mi] = *(const bf16x8*)&sA[buf][row][(q ^ ((row >> 1) & 3)) * 8];
        }
#pragma unroll
        for (int ni = 0; ni < 4; ni++) {
            const int row = wc * 64 + ni * 16 + lm;
            bv[ni] = *(const bf16x8*)&sB[buf][row][(q ^ ((row >> 1) & 3)) * 8];
        }
#pragma unroll
        for (int mi = 0; mi < 4; mi++)
#pragma unroll
            for (int ni = 0; ni < 4; ni++)
                acc[mi][ni] = __builtin_amdgcn_mfma_f32_16x16x32_bf16(
                    av[mi], bv[ni], acc[mi][ni], 0, 0, 0);
    }
    __syncthreads();   // K-loop done; LDS red[] is now writable scratch

    const int colb = wc * 64;
    float bsv[4];
#pragma unroll
    for (int ni = 0; ni < 4; ni++) bsv[ni] = bias[colb + ni * 16 + lm];

    // v = C + bias + residual (in place), accumulate row partials, reduce
#pragma unroll
    for (int mi = 0; mi < 4; mi++) {
#pragma unroll
        for (int rr = 0; rr < 4; rr++) {
            const int lr = mi * 16 + q4 + rr;
            const size_t gb = (size_t)(row0 + lr) * 256 + colb + lm;
            float s = 0.f, sq = 0.f;
#pragma unroll
            for (int ni = 0; ni < 4; ni++) {
                float v = acc[mi][ni][rr] + bsv[ni] + R[gb + ni * 16];
                acc[mi][ni][rr] = v;
                s += v; sq += v * v;
            }
#pragma unroll
            for (int o = 1; o < 16; o <<= 1) {
                s  += __shfl_xor(s, o);
                sq += __shfl_xor(sq, o);
            }
            if (lm == 0) { red[lr][wc] = s; red[lr][4 + wc] = sq; }
        }
    }
    __syncthreads();

    if (tid < 64) {
        float s  = red[tid][0] + red[tid][1] + red[tid][2] + red[tid][3];
        float sq = red[tid][4] + red[tid][5] + red[tid][6] + red[tid][7];
        float mean = s * (1.f / 256.f);
        float var  = sq * (1.f / 256.f) - mean * mean;
        red[tid][8] = mean;
        red[tid][9] = rsqrtf(fmaxf(var, 0.f) + 1e-5f);
    }
    __syncthreads();

    float w4v[4], b4v[4];
#pragma unroll
    for (int ni = 0; ni < 4; ni++) {
        w4v[ni] = lnw[colb + ni * 16 + lm];
        b4v[ni] = lnb[colb + ni * 16 + lm];
    }
#pragma unroll
    for (int mi = 0; mi < 4; mi++) {
#pragma unroll
        for (int rr = 0; rr < 4; rr++) {
            const int lr = mi * 16 + q4 + rr;
            const float mean = red[lr][8], rs = red[lr][9];
            const size_t gb = (size_t)(row0 + lr) * 256 + colb + lm;
#pragma unroll
            for (int ni = 0; ni < 4; ni++) {
                const float y = (acc[mi][ni][rr] - mean) * rs * w4v[ni] + b4v[ni];
                outF[gb + ni * 16] = y;
                if (WRITE2) {
                    float z = y;
                    if (ADDQ) z += qpos[gb + ni * 16];
                    out2[gb + ni * 16] = f2bf(z);
                }
            }
        }
    }
}

// ---------------------------------------------------------------------------
// Self-attention over NC=16 groups; bf16 LDS, padded rows (conflict-free).
// ---------------------------------------------------------------------------
__global__ __launch_bounds__(256) void attn16(
    const unsigned short* __restrict__ QK, const unsigned short* __restrict__ V,
    unsigned short* __restrict__ O)
{
    __shared__ unsigned short sqk[16][520];
    __shared__ unsigned short sv[16][264];
    __shared__ float sp[128][17];

    const int g = blockIdx.x;
    const int tid = threadIdx.x;

    const uint4* qg = (const uint4*)(QK + (size_t)g * 8192);
    for (int i = tid; i < 1024; i += 256)
        *(uint4*)&sqk[i >> 6][(i & 63) * 8] = qg[i];
    const uint4* vg = (const uint4*)(V + (size_t)g * 4096);
    for (int i = tid; i < 512; i += 256)
        *(uint4*)&sv[i >> 5][(i & 31) * 8] = vg[i];
    __syncthreads();

#pragma unroll 2
    for (int s = tid; s < 2048; s += 256) {
        const int h = s >> 8, qi = (s >> 4) & 15, kj = s & 15;
        const uint4* qp = (const uint4*)&sqk[qi][h * 32];
        const uint4* kp = (const uint4*)&sqk[kj][256 + h * 32];
        float acc = 0.f;
#pragma unroll
        for (int c = 0; c < 4; c++) {
            uint4 qu = qp[c];
            uint4 ku = kp[c];
            acc += bf_lo(qu.x) * bf_lo(ku.x) + bf_hi(qu.x) * bf_hi(ku.x)
                 + bf_lo(qu.y) * bf_lo(ku.y) + bf_hi(qu.y) * bf_hi(ku.y)
                 + bf_lo(qu.z) * bf_lo(ku.z) + bf_hi(qu.z) * bf_hi(ku.z)
                 + bf_lo(qu.w) * bf_lo(ku.w) + bf_hi(qu.w) * bf_hi(ku.w);
        }
        sp[s >> 4][s & 15] = acc * 0.17677669529663687f;
    }
    __syncthreads();

    if (tid < 128) {
        float* row = sp[tid];
        float mx = row[0];
#pragma unroll
        for (int j = 1; j < 16; j++) mx = fmaxf(mx, row[j]);
        float sum = 0.f;
#pragma unroll
        for (int j = 0; j < 16; j++) { float e = __expf(row[j] - mx); row[j] = e; sum += e; }
        float inv = 1.f / sum;
#pragma unroll
        for (int j = 0; j < 16; j++) row[j] *= inv;
    }
    __syncthreads();

    uint2* og = (uint2*)(O + (size_t)g * 4096);
    for (int o = tid; o < 1024; o += 256) {
        const int qi = o >> 6, cq = o & 63, h = cq >> 3;
        const float* pr = sp[h * 16 + qi];
        float a0 = 0.f, a1 = 0.f, a2 = 0.f, a3 = 0.f;
#pragma unroll
        for (int j = 0; j < 16; j++) {
            uint2 u = *(const uint2*)&sv[j][cq * 4];
            float p = pr[j];
            a0 += p * bf_lo(u.x); a1 += p * bf_hi(u.x);
            a2 += p * bf_lo(u.y); a3 += p * bf_hi(u.y);
        }
        uint2 r; r.x = pk_bf16(a0, a1); r.y = pk_bf16(a2, a3);
        og[o] = r;
    }
}

// ---------------------------------------------------------------------------
// MS-deformable sampling v4: as v3 (256 thr, 8 q/block, 2 q/wave, 16-B lane
// slices, one batch per XCD chunk) + phase-3 explicit 2-deep software
// pipeline: j+1's table reads and 4 corner gathers issued into named "next"
// registers before j's FMA block -> ~8 loads in flight (was 4, VGPR 40 JIT
// scheduling), hiding L2 latency under the 64-FMA chain.
// ---------------------------------------------------------------------------
__global__ __launch_bounds__(256) void ms_sample4p(
    const unsigned short* __restrict__ VAL, const unsigned short* __restrict__ OFF,
    const float* __restrict__ AWL, const float* __restrict__ REF,
    unsigned short* __restrict__ OUT)
{
    __shared__ char smem[24576];
    unsigned short* soff = (unsigned short*)smem;            // [8][256]   (A)
    float*          saw  = (float*)(smem + 4096);            // [8][128]   (A)
    float*          sref = (float*)(smem + 8192);            // [8][8]     (A)
    float*          swt  = (float*)smem;                     // [8][16][8][4]   (B)
    unsigned short* sidx = (unsigned short*)(smem + 16384);  // [8][16][8][4]   (B)

    const int wblk = xcd_swz(blockIdx.x, 4800);
    const int m0 = wblk * 8, tid = threadIdx.x;

    ((uint4*)soff)[tid]  = ((const uint4*)(OFF + (size_t)m0 * 256))[tid];
    ((float4*)saw)[tid]  = ((const float4*)(AWL + (size_t)m0 * 128))[tid];
    if (tid < 64) sref[tid] = REF[(size_t)m0 * 8 + tid];
    __syncthreads();

    // softmax over 16 logits per (q,h): 64 rows, all 256 threads
    {
        const int row = tid >> 2, part = tid & 3;
        float4 lg = *(float4*)&saw[row * 16 + part * 4];
        float mx = fmaxf(fmaxf(lg.x, lg.y), fmaxf(lg.z, lg.w));
        mx = fmaxf(mx, __shfl_xor(mx, 1));
        mx = fmaxf(mx, __shfl_xor(mx, 2));
        float e0 = __expf(lg.x - mx), e1 = __expf(lg.y - mx);
        float e2 = __expf(lg.z - mx), e3 = __expf(lg.w - mx);
        float s = e0 + e1 + e2 + e3;
        s += __shfl_xor(s, 1);
        s += __shfl_xor(s, 2);
        const float inv = 1.f / s;
        float4 pr; pr.x = e0 * inv; pr.y = e1 * inv; pr.z = e2 * inv; pr.w = e3 * inv;
        *(float4*)&saw[row * 16 + part * 4] = pr;
    }
    __syncthreads();

    // decode 1024 items (4/thread) into registers
    float4  w4r[4];
    ushort4 rr4[4];
#pragma unroll
    for (int k = 0; k < 4; k++) {
        const int c = tid + k * 256;
        const int qi = c >> 7, h = c & 7, j = (c >> 3) & 15;
        const int l = j >> 2, p = j & 3;
        const int Wl = 64 >> l;
        const int st = (l == 0) ? 0 : (l == 1) ? 4096 : (l == 2) ? 5120 : 5376;
        const float fS = (float)Wl;
        const unsigned short* ob = &soff[qi * 256 + h * 32 + l * 8 + p * 2];
        const float x = sref[qi * 8 + l * 2 + 0] * fS + bf1(ob[0]) - 0.5f;
        const float y = sref[qi * 8 + l * 2 + 1] * fS + bf1(ob[1]) - 0.5f;
        const float x0f = floorf(x), y0f = floorf(y);
        const float fx = x - x0f, fy = y - y0f;
        const int x0 = (int)x0f, y0 = (int)y0f;
        const int x1 = x0 + 1, y1 = y0 + 1;
        const float vx0 = (x0 >= 0 && x0 < Wl) ? 1.f : 0.f;
        const float vx1 = (x1 >= 0 && x1 < Wl) ? 1.f : 0.f;
        const float vy0 = (y0 >= 0 && y0 < Wl) ? 1.f : 0.f;
        const float vy1 = (y1 >= 0 && y1 < Wl) ? 1.f : 0.f;
        const int cx0 = min(max(x0, 0), Wl - 1);
        const int cx1 = min(max(x1, 0), Wl - 1);
        const int cy0 = min(max(y0, 0), Wl - 1);
        const int cy1 = min(max(y1, 0), Wl - 1);
        const float aw = saw[qi * 128 + h * 16 + j];
        w4r[k].x = (1.f - fx) * (1.f - fy) * vx0 * vy0 * aw;
        w4r[k].y = fx * (1.f - fy) * vx1 * vy0 * aw;
        w4r[k].z = (1.f - fx) * fy * vx0 * vy1 * aw;
        w4r[k].w = fx * fy * vx1 * vy1 * aw;
        rr4[k].x = (unsigned short)(st + cy0 * Wl + cx0);
        rr4[k].y = (unsigned short)(st + cy0 * Wl + cx1);
        rr4[k].z = (unsigned short)(st + cy1 * Wl + cx0);
        rr4[k].w = (unsigned short)(st + cy1 * Wl + cx1);
    }
    __syncthreads();   // region A dead; write region B

#pragma unroll
    for (int k = 0; k < 4; k++) {
        const int c = tid + k * 256;
        const int qi = c >> 7, h = c & 7, j = (c >> 3) & 15;
        *(float4*)&swt[((qi * 16 + j) * 8 + h) * 4]   = w4r[k];
        *(ushort4*)&sidx[((qi * 16 + j) * 8 + h) * 4] = rr4[k];
    }
    __syncthreads();

    // gather + weighted accumulate, 2-deep software pipeline
    const int qi = tid >> 5;
    const int l31 = tid & 31;
    const int h = l31 >> 2;
    const unsigned loff = (unsigned)l31 * 16;
    const int m = m0 + qi;
    const char* vbase = (const char*)VAL + (size_t)(m0 / 4800) * 5440 * 512;
    const int sbase = qi * 512 + h * 4;   // float/ushort index; +32 per j

    float4  w  = *(const float4*)&swt[sbase];
    ushort4 rw = *(const ushort4*)&sidx[sbase];
    uint4 c0 = *(const uint4*)(vbase + (((unsigned)rw.x << 9) + loff));
    uint4 c1 = *(const uint4*)(vbase + (((unsigned)rw.y << 9) + loff));
    uint4 c2 = *(const uint4*)(vbase + (((unsigned)rw.z << 9) + loff));
    uint4 c3 = *(const uint4*)(vbase + (((unsigned)rw.w << 9) + loff));

    f32x2 a0 = {0.f, 0.f}, a1 = {0.f, 0.f}, a2 = {0.f, 0.f}, a3 = {0.f, 0.f};
#pragma unroll
    for (int j = 0; j < 16; j++) {
        float4 wn = w; uint4 n0 = c0, n1 = c1, n2 = c2, n3 = c3;
        if (j < 15) {
            const int nb = sbase + (j + 1) * 32;
            wn = *(const float4*)&swt[nb];
            const ushort4 rn = *(const ushort4*)&sidx[nb];
            n0 = *(const uint4*)(vbase + (((unsigned)rn.x << 9) + loff));
            n1 = *(const uint4*)(vbase + (((unsigned)rn.y << 9) + loff));
            n2 = *(const uint4*)(vbase + (((unsigned)rn.z << 9) + loff));
            n3 = *(const uint4*)(vbase + (((unsigned)rn.w << 9) + loff));
        }
        a0 += w.x * bfpair(c0.x); a1 += w.x * bfpair(c0.y);
        a2 += w.x * bfpair(c0.z); a3 += w.x * bfpair(c0.w);
        a0 += w.y * bfpair(c1.x); a1 += w.y * bfpair(c1.y);
        a2 += w.y * bfpair(c1.z); a3 += w.y * bfpair(c1.w);
        a0 += w.z * bfpair(c2.x); a1 += w.z * bfpair(c2.y);
        a2 += w.z * bfpair(c2.z); a3 += w.z * bfpair(c2.w);
        a0 += w.w * bfpair(c3.x); a1 += w.w * bfpair(c3.y);
        a2 += w.w * bfpair(c3.z); a3 += w.w * bfpair(c3.w);
        w = wn; c0 = n0; c1 = n1; c2 = n2; c3 = n3;
    }
    uint4 o;
    o.x = pk_bf16(a0.x, a0.y);
    o.y = pk_bf16(a1.x, a1.y);
    o.z = pk_bf16(a2.x, a2.y);
    o.w = pk_bf16(a3.x, a3.y);
    *(uint4*)(OUT + (size_t)m * 256 + l31 * 8) = o;
}

// ---------------------------------------------------------------------------
// Launch
// ---------------------------------------------------------------------------
extern "C" void kernel_launch(void* const* d_in, const int* in_sizes, int n_in,
                              void* d_out, int out_size, void* d_ws, size_t ws_size,
                              hipStream_t stream)
{
    const float* tgt        = (const float*)d_in[0];
    const float* qpos       = (const float*)d_in[1];
    const float* refp       = (const float*)d_in[2];
    const float* src        = (const float*)d_in[3];
    const float* sa_in_w    = (const float*)d_in[7];
    const float* sa_in_b    = (const float*)d_in[8];
    const float* sa_out_w   = (const float*)d_in[9];
    const float* sa_out_b   = (const float*)d_in[10];
    const float* norm2_w    = (const float*)d_in[11];
    const float* norm2_b    = (const float*)d_in[12];
    const float* ca_value_w = (const float*)d_in[13];
    const float* ca_value_b = (const float*)d_in[14];
    const float* ca_off_w   = (const float*)d_in[15];
    const float* ca_off_b   = (const float*)d_in[16];
    const float* ca_attw_w  = (const float*)d_in[17];
    const float* ca_attw_b  = (const float*)d_in[18];
    const float* ca_out_w   = (const float*)d_in[19];
    const float* ca_out_b   = (const float*)d_in[20];
    const float* norm1_w    = (const float*)d_in[21];
    const float* norm1_b    = (const float*)d_in[22];
    const float* lin1_w     = (const float*)d_in[23];
    const float* lin1_b     = (const float*)d_in[24];
    const float* lin2_w     = (const float*)d_in[25];
    const float* lin2_b     = (const float*)d_in[26];
    const float* norm3_w    = (const float*)d_in[27];
    const float* norm3_b    = (const float*)d_in[28];
    float* out = (float*)d_out;

    float* ws = (float*)d_ws;
    float* A  = ws;
    float* Bx = A  + 9830400;
    float* Cx = Bx + 4915200;
    float* Dx = Cx + 4915200;
    float* Ex = Dx + 4915200;
    float* Fx = Ex + 5570560;
    float* Gx = Fx + 19660800;

    unsigned short* qkB   = (unsigned short*)A;
    float*          t1    = A;
    float*          t2    = A;
    unsigned short* vB    = (unsigned short*)Bx;
    unsigned short* t1qB  = (unsigned short*)Bx;
    unsigned short* sampB = (unsigned short*)Bx;
    unsigned short* aoB   = (unsigned short*)Cx;
    unsigned short* offB  = (unsigned short*)Cx;
    unsigned short* t2B   = (unsigned short*)Cx;
    float*          awL   = Dx;
    unsigned short* valB  = (unsigned short*)Ex;
    unsigned short* hidB  = (unsigned short*)Fx;
    unsigned short* wG    = (unsigned short*)Gx;

    // bf16 activation staging lives in Fx (dead before hidB is written at FFN1)
    unsigned short* qBa   = (unsigned short*)Fx;
    unsigned short* tgtBa = qBa + 9830400;
    unsigned short* srcBa = tgtBa + 9830400;

    unsigned short* wSAIN  = wG;            // 768*256
    unsigned short* wSAOUT = wG + 196608;   // 256*256
    unsigned short* wVAL   = wG + 262144;   // 256*256
    unsigned short* wOFF   = wG + 327680;   // 256*256
    unsigned short* wATT   = wG + 393216;   // 128*256
    unsigned short* wCAOUT = wG + 425984;   // 256*256
    unsigned short* wL1    = wG + 491520;   // 1024*256
    unsigned short* wL2    = wG + 753664;   // 256*1024

    dim3 blk(256);

    WcvtArgs wa;
    wa.src[0] = sa_in_w;    wa.dst[0] = wSAIN;  wa.n4[0] = 196608 / 4;
    wa.src[1] = sa_out_w;   wa.dst[1] = wSAOUT; wa.n4[1] = 65536 / 4;
    wa.src[2] = ca_value_w; wa.dst[2] = wVAL;   wa.n4[2] = 65536 / 4;
    wa.src[3] = ca_off_w;   wa.dst[3] = wOFF;   wa.n4[3] = 65536 / 4;
    wa.src[4] = ca_attw_w;  wa.dst[4] = wATT;   wa.n4[4] = 32768 / 4;
    wa.src[5] = ca_out_w;   wa.dst[5] = wCAOUT; wa.n4[5] = 65536 / 4;
    wa.src[6] = lin1_w;     wa.dst[6] = wL1;    wa.n4[6] = 262144 / 4;
    wa.src[7] = lin2_w;     wa.dst[7] = wL2;    wa.n4[7] = 262144 / 4;
    wcvt<<<512, blk, 0, stream>>>(wa);
    cvt_acts<<<2048, blk, 0, stream>>>(tgt, qpos, src, tgtBa, qBa, srcBa);

    // --- self-attention (+ value GEMM fused in) ---
    gemm_qkvval<<<dim3(8, 340), blk, 0, stream>>>(qBa, tgtBa, srcBa, wSAIN, sa_in_b,
                                                  qkB, vB, wVAL, ca_value_b, valB);
    attn16<<<2400, blk, 0, stream>>>(qkB, vB, aoB);
    gemm_ln64<1, 1><<<600, blk, 0, stream>>>(aoB, wSAOUT, sa_out_b, tgt,
                                             norm2_w, norm2_b, t1, t1qB, qpos,
                                             256, 600);

    // --- MS deformable cross-attention ---
    gemm_offaw<<<dim3(3, 300), blk, 0, stream>>>(t1qB, wOFF, ca_off_b, offB, wATT, ca_attw_b, awL);
    ms_sample4p<<<4800, blk, 0, stream>>>(valB, offB, awL, refp, sampB);
    gemm_ln64<1, 0><<<600, blk, 0, stream>>>(sampB, wCAOUT, ca_out_b, t1,
                                             norm1_w, norm1_b, t2, t2B, nullptr,
                                             256, 600);

    // --- FFN ---
    gemm_std128<<<dim3(8, 300), blk, 0, stream>>>(t2B, wL1, lin1_b, hidB, 1, 1, 1024, 256);
    gemm_ln64<0, 0><<<600, blk, 0, stream>>>(hidB, wL2, lin2_b, t2,
                                             norm3_w, norm3_b, out, nullptr, nullptr,
                                             1024, 600);
}

// Round 8
// 613.827 us; speedup vs baseline: 1.0788x; 1.0788x over previous
//
#include <hip/hip_runtime.h>

// ---------------------------------------------------------------------------
// D=256 HEADS=8 DH=32 LEVELS=4 POINTS=4 DFFN=1024 B=8 NQ=300 NC=16
// M1 = 38400, LEN_IN = 5440, value rows = 43520
// SPATIAL = (64,64),(32,32),(16,16),(8,8); level starts 0,4096,5120,5376
// ---------------------------------------------------------------------------

typedef __bf16 bf16x8 __attribute__((ext_vector_type(8)));
typedef float  f32x4  __attribute__((ext_vector_type(4)));
typedef float  f32x2  __attribute__((ext_vector_type(2)));

__device__ __forceinline__ unsigned pk_bf16(float lo, float hi)
{
    unsigned a = __float_as_uint(lo) + 0x8000u;
    unsigned b = __float_as_uint(hi) + 0x8000u;
    return __builtin_amdgcn_perm(b, a, 0x07060302u);
}
__device__ __forceinline__ unsigned short f2bf(float v)
{
    return (unsigned short)((__float_as_uint(v) + 0x8000u) >> 16);
}
__device__ __forceinline__ float bf_lo(unsigned u) { return __uint_as_float(u << 16); }
__device__ __forceinline__ float bf_hi(unsigned u) { return __uint_as_float(u & 0xffff0000u); }
__device__ __forceinline__ float bf1(unsigned short u) { return __uint_as_float((unsigned)u << 16); }
__device__ __forceinline__ f32x2 bfpair(unsigned u)
{
    f32x2 r;
    r.x = __uint_as_float(u << 16);
    r.y = __uint_as_float(u & 0xffff0000u);
    return r;
}

// XCD-aware chunked block swizzle (bijective for any nwg; m204 variant).
__device__ __forceinline__ int xcd_swz(int wgid, int nwg)
{
    const int q = nwg >> 3, r = nwg & 7;
    const int x = wgid & 7, k = wgid >> 3;
    return (x < r ? x * (q + 1) : r * (q + 1) + (x - r) * q) + k;
}

// async global->LDS, 16 B per lane. LDS dest must be wave-uniform base + lane*16.
__device__ __forceinline__ void gl_lds16(const unsigned short* g, unsigned short* l)
{
    __builtin_amdgcn_global_load_lds(
        (const __attribute__((address_space(1))) unsigned int*)g,
        (__attribute__((address_space(3))) unsigned int*)l,
        16, 0, 0);
}

// ---------------------------------------------------------------------------
// Weight pre-conversion fp32 -> bf16 (8 segments, one dispatch).
// ---------------------------------------------------------------------------
struct WcvtArgs {
    const float* src[8];
    unsigned short* dst[8];
    int n4[8];
};

__global__ __launch_bounds__(256) void wcvt(WcvtArgs a)
{
    const int gid = blockIdx.x * 256 + threadIdx.x;
    const int stride = gridDim.x * 256;
#pragma unroll
    for (int s = 0; s < 8; s++) {
        const float4* sp = (const float4*)a.src[s];
        uint2* dp = (uint2*)a.dst[s];
        for (int i = gid; i < a.n4[s]; i += stride) {
            float4 f = sp[i];
            uint2 o; o.x = pk_bf16(f.x, f.y); o.y = pk_bf16(f.z, f.w);
            dp[i] = o;
        }
    }
}

// ---------------------------------------------------------------------------
// Activation pre-conversion: tgtB = bf16(tgt), qB = bf16(tgt+qpos),
// srcB = bf16(src). Makes all GEMM A-operands bf16 (global_load_lds path).
// ---------------------------------------------------------------------------
__global__ __launch_bounds__(256) void cvt_acts(
    const float* __restrict__ tgt, const float* __restrict__ qpos,
    const float* __restrict__ src,
    unsigned short* __restrict__ tgtB, unsigned short* __restrict__ qB,
    unsigned short* __restrict__ srcB)
{
    const int gid = blockIdx.x * 256 + threadIdx.x;
    const int stride = gridDim.x * 256;
    for (int i = gid; i < 2457600; i += stride) {          // 38400*256/4
        float4 t = ((const float4*)tgt)[i];
        float4 p = ((const float4*)qpos)[i];
        uint2 a; a.x = pk_bf16(t.x, t.y); a.y = pk_bf16(t.z, t.w);
        ((uint2*)tgtB)[i] = a;
        uint2 b; b.x = pk_bf16(t.x + p.x, t.y + p.y);
        b.y = pk_bf16(t.z + p.z, t.w + p.w);
        ((uint2*)qB)[i] = b;
    }
    for (int i = gid; i < 2785280; i += stride) {          // 8*5440*256/4
        float4 s = ((const float4*)src)[i];
        uint2 c; c.x = pk_bf16(s.x, s.y); c.y = pk_bf16(s.z, s.w);
        ((uint2*)srcB)[i] = c;
    }
}

// ---------------------------------------------------------------------------
// GEMM core (m97 structure): 128x128 tile, BK=32, double-buffered LDS,
// global_load_lds width=16 staging, one barrier per K-step. 4 waves (2x2).
// Both-sides XOR slot-swizzle (slot ^= (row>>1)&3).
// A is bf16 [M,K]; W is bf16 [N,K]; C row-major [M,N].
// ---------------------------------------------------------------------------
__device__ __forceinline__ void gemm_core128(
    const unsigned short* __restrict__ Ab,
    const unsigned short* __restrict__ Wb, const float* __restrict__ bias,
    void* __restrict__ Cv, int outbf16, int relu,
    int row0, int col0, int N, int K,
    unsigned short (*sA)[128][32], unsigned short (*sB)[128][32])
{
    const int tid  = threadIdx.x;
    const int lane = tid & 63;
    const int wv   = tid >> 6;
    const int wr   = wv >> 1;
    const int wc   = wv & 1;
    const int lm   = lane & 15;
    const int q    = lane >> 4;
    const int q4   = q << 2;

    const int tr = tid >> 2;
    const int ts = tid & 3;

    f32x4 acc[4][4] = {};
    const int iters = K >> 5;

    auto stage = [&](int buf, int k) {
#pragma unroll
        for (int r = 0; r < 2; ++r) {
            const int row = r * 64 + tr;
            const int sw  = ts ^ ((row >> 1) & 3);
            gl_lds16(Ab + (size_t)(row0 + row) * K + k + sw * 8,
                     &sA[buf][0][0] + (size_t)(r * 256 + tid) * 8);
            gl_lds16(Wb + (size_t)(col0 + row) * K + k + sw * 8,
                     &sB[buf][0][0] + (size_t)(r * 256 + tid) * 8);
        }
    };

    stage(0, 0);

    for (int it = 0; it < iters; ++it) {
        __syncthreads();
        const int buf = it & 1;
        if (it + 1 < iters) stage(buf ^ 1, (it + 1) << 5);

        bf16x8 av[4], bv[4];
#pragma unroll
        for (int mi = 0; mi < 4; mi++) {
            const int row = wr * 64 + mi * 16 + lm;
            av[mi] = *(const bf16x8*)&sA[buf][row][(q ^ ((row >> 1) & 3)) * 8];
        }
#pragma unroll
        for (int ni = 0; ni < 4; ni++) {
            const int row = wc * 64 + ni * 16 + lm;
            bv[ni] = *(const bf16x8*)&sB[buf][row][(q ^ ((row >> 1) & 3)) * 8];
        }
#pragma unroll
        for (int mi = 0; mi < 4; mi++)
#pragma unroll
            for (int ni = 0; ni < 4; ni++)
                acc[mi][ni] = __builtin_amdgcn_mfma_f32_16x16x32_bf16(
                    av[mi], bv[ni], acc[mi][ni], 0, 0, 0);
    }

#pragma unroll
    for (int ni = 0; ni < 4; ni++) {
        const int col = col0 + wc * 64 + ni * 16 + lm;
        const float bsv = bias[col];
#pragma unroll
        for (int mi = 0; mi < 4; mi++) {
            const int rowb = row0 + wr * 64 + mi * 16 + q4;
#pragma unroll
            for (int rr = 0; rr < 4; rr++) {
                float v = acc[mi][ni][rr] + bsv;
                if (relu) v = fmaxf(v, 0.f);
                if (outbf16)
                    ((unsigned short*)Cv)[(size_t)(rowb + rr) * N + col] = f2bf(v);
                else
                    ((float*)Cv)[(size_t)(rowb + rr) * N + col] = v;
            }
        }
    }
}

__global__ __launch_bounds__(256) void gemm_std128(
    const unsigned short* __restrict__ Ab,
    const unsigned short* __restrict__ Wb, const float* __restrict__ bias,
    void* __restrict__ Cv, int outbf16, int relu, int N, int K)
{
    __shared__ unsigned short sA[2][128][32];
    __shared__ unsigned short sB[2][128][32];
    const int nwg = gridDim.x * gridDim.y;
    const int w = xcd_swz(blockIdx.x + gridDim.x * blockIdx.y, nwg);
    const int x = w % gridDim.x, y = w / gridDim.x;
    gemm_core128(Ab, Wb, bias, Cv, outbf16, relu,
                 y * 128, x * 128, N, K, sA, sB);
}

// fused: qk = qB@Wqk^T (N=512, x=0..3), v = tgtB@Wv^T (x=4..5),
// value = srcB@Wval^T over 43520 rows (x=6..7). grid (8, 340).
__global__ __launch_bounds__(256) void gemm_qkvval(
    const unsigned short* __restrict__ qB, const unsigned short* __restrict__ tgtB,
    const unsigned short* __restrict__ srcB,
    const unsigned short* __restrict__ Wsa, const float* __restrict__ bsa,
    unsigned short* __restrict__ qkB, unsigned short* __restrict__ vB,
    const unsigned short* __restrict__ Wval, const float* __restrict__ bval,
    unsigned short* __restrict__ valB)
{
    __shared__ unsigned short sA[2][128][32];
    __shared__ unsigned short sB[2][128][32];
    const int w = xcd_swz(blockIdx.x + 8 * blockIdx.y, 2720);
    const int x = w & 7, y = w >> 3;
    if (x < 4) {
        if (y >= 300) return;
        gemm_core128(qB, Wsa, bsa, qkB, 1, 0, y * 128, x * 128, 512, 256, sA, sB);
    } else if (x < 6) {
        if (y >= 300) return;
        gemm_core128(tgtB, Wsa + 512 * 256, bsa + 512, vB, 1, 0,
                     y * 128, (x - 4) * 128, 256, 256, sA, sB);
    } else {
        gemm_core128(srcB, Wval, bval, valB, 1, 0,
                     y * 128, (x - 6) * 128, 256, 256, sA, sB);
    }
}

// fused: off (N=256, x=0..1, bf16 out) and attw logits (N=128, x=2, fp32 out)
__global__ __launch_bounds__(256) void gemm_offaw(
    const unsigned short* __restrict__ X,
    const unsigned short* __restrict__ Woff, const float* __restrict__ boff,
    unsigned short* __restrict__ offB,
    const unsigned short* __restrict__ Watt, const float* __restrict__ batt,
    float* __restrict__ awL)
{
    __shared__ unsigned short sA[2][128][32];
    __shared__ unsigned short sB[2][128][32];
    const int w = xcd_swz(blockIdx.x + 3 * blockIdx.y, 900);
    const int x = w % 3, y = w / 3;
    if (x >= 2)
        gemm_core128(X, Watt, batt, awL, 0, 0,
                     y * 128, 0, 128, 256, sA, sB);
    else
        gemm_core128(X, Woff, boff, offB, 1, 0,
                     y * 128, x * 128, 256, 256, sA, sB);
}

// ---------------------------------------------------------------------------
// Self-attention over NC=16 groups; bf16 LDS, padded rows (conflict-free).
// ---------------------------------------------------------------------------
__global__ __launch_bounds__(256) void attn16(
    const unsigned short* __restrict__ QK, const unsigned short* __restrict__ V,
    unsigned short* __restrict__ O)
{
    __shared__ unsigned short sqk[16][520];
    __shared__ unsigned short sv[16][264];
    __shared__ float sp[128][17];

    const int g = blockIdx.x;
    const int tid = threadIdx.x;

    const uint4* qg = (const uint4*)(QK + (size_t)g * 8192);
    for (int i = tid; i < 1024; i += 256)
        *(uint4*)&sqk[i >> 6][(i & 63) * 8] = qg[i];
    const uint4* vg = (const uint4*)(V + (size_t)g * 4096);
    for (int i = tid; i < 512; i += 256)
        *(uint4*)&sv[i >> 5][(i & 31) * 8] = vg[i];
    __syncthreads();

#pragma unroll 2
    for (int s = tid; s < 2048; s += 256) {
        const int h = s >> 8, qi = (s >> 4) & 15, kj = s & 15;
        const uint4* qp = (const uint4*)&sqk[qi][h * 32];
        const uint4* kp = (const uint4*)&sqk[kj][256 + h * 32];
        float acc = 0.f;
#pragma unroll
        for (int c = 0; c < 4; c++) {
            uint4 qu = qp[c];
            uint4 ku = kp[c];
            acc += bf_lo(qu.x) * bf_lo(ku.x) + bf_hi(qu.x) * bf_hi(ku.x)
                 + bf_lo(qu.y) * bf_lo(ku.y) + bf_hi(qu.y) * bf_hi(ku.y)
                 + bf_lo(qu.z) * bf_lo(ku.z) + bf_hi(qu.z) * bf_hi(ku.z)
                 + bf_lo(qu.w) * bf_lo(ku.w) + bf_hi(qu.w) * bf_hi(ku.w);
        }
        sp[s >> 4][s & 15] = acc * 0.17677669529663687f;
    }
    __syncthreads();

    if (tid < 128) {
        float* row = sp[tid];
        float mx = row[0];
#pragma unroll
        for (int j = 1; j < 16; j++) mx = fmaxf(mx, row[j]);
        float sum = 0.f;
#pragma unroll
        for (int j = 0; j < 16; j++) { float e = __expf(row[j] - mx); row[j] = e; sum += e; }
        float inv = 1.f / sum;
#pragma unroll
        for (int j = 0; j < 16; j++) row[j] *= inv;
    }
    __syncthreads();

    uint2* og = (uint2*)(O + (size_t)g * 4096);
    for (int o = tid; o < 1024; o += 256) {
        const int qi = o >> 6, cq = o & 63, h = cq >> 3;
        const float* pr = sp[h * 16 + qi];
        float a0 = 0.f, a1 = 0.f, a2 = 0.f, a3 = 0.f;
#pragma unroll
        for (int j = 0; j < 16; j++) {
            uint2 u = *(const uint2*)&sv[j][cq * 4];
            float p = pr[j];
            a0 += p * bf_lo(u.x); a1 += p * bf_hi(u.x);
            a2 += p * bf_lo(u.y); a3 += p * bf_hi(u.y);
        }
        uint2 r; r.x = pk_bf16(a0, a1); r.y = pk_bf16(a2, a3);
        og[o] = r;
    }
}

// ---------------------------------------------------------------------------
// Residual + LN, wave-per-row (4 rows/block), butterfly shuffles, no LDS.
// ---------------------------------------------------------------------------
template <int XBF16, int WRITE2, int ADDQ>
__global__ __launch_bounds__(256) void ln_res4(
    const void* __restrict__ Xv, const float* __restrict__ R,
    const float* __restrict__ w, const float* __restrict__ b,
    float* __restrict__ out, unsigned short* __restrict__ out2,
    const float* __restrict__ qpos)
{
    const int row = blockIdx.x * 4 + (threadIdx.x >> 6);
    const int lane = threadIdx.x & 63;
    const size_t base = (size_t)row * 256 + lane * 4;

    float x0, x1, x2, x3;
    if (XBF16) {
        uint2 u = *(const uint2*)((const unsigned short*)Xv + base);
        x0 = bf_lo(u.x); x1 = bf_hi(u.x); x2 = bf_lo(u.y); x3 = bf_hi(u.y);
    } else {
        float4 f = *(const float4*)((const float*)Xv + base);
        x0 = f.x; x1 = f.y; x2 = f.z; x3 = f.w;
    }
    float4 r4 = *(const float4*)&R[base];
    float v0 = x0 + r4.x, v1 = x1 + r4.y, v2 = x2 + r4.z, v3 = x3 + r4.w;

    float s = v0 + v1 + v2 + v3;
#pragma unroll
    for (int o = 32; o > 0; o >>= 1) s += __shfl_xor(s, o);
    const float mean = s * (1.f / 256.f);
    const float d0 = v0 - mean, d1 = v1 - mean, d2 = v2 - mean, d3 = v3 - mean;
    float qv = d0 * d0 + d1 * d1 + d2 * d2 + d3 * d3;
#pragma unroll
    for (int o = 32; o > 0; o >>= 1) qv += __shfl_xor(qv, o);
    const float rs = rsqrtf(qv * (1.f / 256.f) + 1e-5f);

    float4 w4 = *(const float4*)&w[lane * 4];
    float4 b4 = *(const float4*)&b[lane * 4];
    float y0 = d0 * rs * w4.x + b4.x;
    float y1 = d1 * rs * w4.y + b4.y;
    float y2 = d2 * rs * w4.z + b4.z;
    float y3 = d3 * rs * w4.w + b4.w;

    float4 o4; o4.x = y0; o4.y = y1; o4.z = y2; o4.w = y3;
    *(float4*)&out[base] = o4;
    if (WRITE2) {
        float z0 = y0, z1 = y1, z2 = y2, z3 = y3;
        if (ADDQ) {
            float4 qp4 = *(const float4*)&qpos[base];
            z0 += qp4.x; z1 += qp4.y; z2 += qp4.z; z3 += qp4.w;
        }
        uint2 u; u.x = pk_bf16(z0, z1); u.y = pk_bf16(z2, z3);
        *(uint2*)(out2 + base) = u;
    }
}

// ---------------------------------------------------------------------------
// MS-deformable sampling v5: R4 structure (256 thr, 8 q/block, 2 q/wave,
// 16-B lane slices, one batch per XCD chunk) + BOUNDED 2-deep prefetch in
// phase 3: sched_barrier(0) at end of each unrolled iteration fences the
// scheduler so only {j+1 loads, j FMAs} share a region — prevents the R5
// failure where all 64 gathers were hoisted (VGPR 256, occupancy 10.8%).
// Register ceiling: cur(16) + next(16) + addr ~= 80 VGPR.
// ---------------------------------------------------------------------------
__global__ __launch_bounds__(256) void ms_sample5(
    const unsigned short* __restrict__ VAL, const unsigned short* __restrict__ OFF,
    const float* __restrict__ AWL, const float* __restrict__ REF,
    unsigned short* __restrict__ OUT)
{
    __shared__ char smem[24576];
    unsigned short* soff = (unsigned short*)smem;            // [8][256]   (A)
    float*          saw  = (float*)(smem + 4096);            // [8][128]   (A)
    float*          sref = (float*)(smem + 8192);            // [8][8]     (A)
    float*          swt  = (float*)smem;                     // [8][16][8][4]   (B)
    unsigned short* sidx = (unsigned short*)(smem + 16384);  // [8][16][8][4]   (B)

    const int wblk = xcd_swz(blockIdx.x, 4800);
    const int m0 = wblk * 8, tid = threadIdx.x;

    ((uint4*)soff)[tid]  = ((const uint4*)(OFF + (size_t)m0 * 256))[tid];
    ((float4*)saw)[tid]  = ((const float4*)(AWL + (size_t)m0 * 128))[tid];
    if (tid < 64) sref[tid] = REF[(size_t)m0 * 8 + tid];
    __syncthreads();

    // softmax over 16 logits per (q,h): 64 rows, all 256 threads
    {
        const int row = tid >> 2, part = tid & 3;
        float4 lg = *(float4*)&saw[row * 16 + part * 4];
        float mx = fmaxf(fmaxf(lg.x, lg.y), fmaxf(lg.z, lg.w));
        mx = fmaxf(mx, __shfl_xor(mx, 1));
        mx = fmaxf(mx, __shfl_xor(mx, 2));
        float e0 = __expf(lg.x - mx), e1 = __expf(lg.y - mx);
        float e2 = __expf(lg.z - mx), e3 = __expf(lg.w - mx);
        float s = e0 + e1 + e2 + e3;
        s += __shfl_xor(s, 1);
        s += __shfl_xor(s, 2);
        const float inv = 1.f / s;
        float4 pr; pr.x = e0 * inv; pr.y = e1 * inv; pr.z = e2 * inv; pr.w = e3 * inv;
        *(float4*)&saw[row * 16 + part * 4] = pr;
    }
    __syncthreads();

    // decode 1024 items (4/thread) into registers
    float4  w4r[4];
    ushort4 rr4[4];
#pragma unroll
    for (int k = 0; k < 4; k++) {
        const int c = tid + k * 256;
        const int qi = c >> 7, h = c & 7, j = (c >> 3) & 15;
        const int l = j >> 2, p = j & 3;
        const int Wl = 64 >> l;
        const int st = (l == 0) ? 0 : (l == 1) ? 4096 : (l == 2) ? 5120 : 5376;
        const float fS = (float)Wl;
        const unsigned short* ob = &soff[qi * 256 + h * 32 + l * 8 + p * 2];
        const float x = sref[qi * 8 + l * 2 + 0] * fS + bf1(ob[0]) - 0.5f;
        const float y = sref[qi * 8 + l * 2 + 1] * fS + bf1(ob[1]) - 0.5f;
        const float x0f = floorf(x), y0f = floorf(y);
        const float fx = x - x0f, fy = y - y0f;
        const int x0 = (int)x0f, y0 = (int)y0f;
        const int x1 = x0 + 1, y1 = y0 + 1;
        const float vx0 = (x0 >= 0 && x0 < Wl) ? 1.f : 0.f;
        const float vx1 = (x1 >= 0 && x1 < Wl) ? 1.f : 0.f;
        const float vy0 = (y0 >= 0 && y0 < Wl) ? 1.f : 0.f;
        const float vy1 = (y1 >= 0 && y1 < Wl) ? 1.f : 0.f;
        const int cx0 = min(max(x0, 0), Wl - 1);
        const int cx1 = min(max(x1, 0), Wl - 1);
        const int cy0 = min(max(y0, 0), Wl - 1);
        const int cy1 = min(max(y1, 0), Wl - 1);
        const float aw = saw[qi * 128 + h * 16 + j];
        w4r[k].x = (1.f - fx) * (1.f - fy) * vx0 * vy0 * aw;
        w4r[k].y = fx * (1.f - fy) * vx1 * vy0 * aw;
        w4r[k].z = (1.f - fx) * fy * vx0 * vy1 * aw;
        w4r[k].w = fx * fy * vx1 * vy1 * aw;
        rr4[k].x = (unsigned short)(st + cy0 * Wl + cx0);
        rr4[k].y = (unsigned short)(st + cy0 * Wl + cx1);
        rr4[k].z = (unsigned short)(st + cy1 * Wl + cx0);
        rr4[k].w = (unsigned short)(st + cy1 * Wl + cx1);
    }
    __syncthreads();   // region A dead; write region B

#pragma unroll
    for (int k = 0; k < 4; k++) {
        const int c = tid + k * 256;
        const int qi = c >> 7, h = c & 7, j = (c >> 3) & 15;
        *(float4*)&swt[((qi * 16 + j) * 8 + h) * 4]   = w4r[k];
        *(ushort4*)&sidx[((qi * 16 + j) * 8 + h) * 4] = rr4[k];
    }
    __syncthreads();

    // gather + weighted accumulate, fenced 2-deep pipeline
    const int qi = tid >> 5;
    const int l31 = tid & 31;
    const int h = l31 >> 2;
    const unsigned loff = (unsigned)l31 * 16;
    const int m = m0 + qi;
    const char* vbase = (const char*)VAL + (size_t)(m0 / 4800) * 5440 * 512;
    const int sbase = qi * 512 + h * 4;   // float/ushort index; +32 per j

    float4  w  = *(const float4*)&swt[sbase];
    ushort4 rw = *(const ushort4*)&sidx[sbase];
    uint4 c0 = *(const uint4*)(vbase + (((unsigned)rw.x << 9) + loff));
    uint4 c1 = *(const uint4*)(vbase + (((unsigned)rw.y << 9) + loff));
    uint4 c2 = *(const uint4*)(vbase + (((unsigned)rw.z << 9) + loff));
    uint4 c3 = *(const uint4*)(vbase + (((unsigned)rw.w << 9) + loff));

    f32x2 a0 = {0.f, 0.f}, a1 = {0.f, 0.f}, a2 = {0.f, 0.f}, a3 = {0.f, 0.f};
#pragma unroll
    for (int j = 0; j < 16; j++) {
        float4 wn = w; uint4 n0 = c0, n1 = c1, n2 = c2, n3 = c3;
        if (j < 15) {
            const int nb = sbase + (j + 1) * 32;
            wn = *(const float4*)&swt[nb];
            const ushort4 rn = *(const ushort4*)&sidx[nb];
            n0 = *(const uint4*)(vbase + (((unsigned)rn.x << 9) + loff));
            n1 = *(const uint4*)(vbase + (((unsigned)rn.y << 9) + loff));
            n2 = *(const uint4*)(vbase + (((unsigned)rn.z << 9) + loff));
            n3 = *(const uint4*)(vbase + (((unsigned)rn.w << 9) + loff));
        }
        a0 += w.x * bfpair(c0.x); a1 += w.x * bfpair(c0.y);
        a2 += w.x * bfpair(c0.z); a3 += w.x * bfpair(c0.w);
        a0 += w.y * bfpair(c1.x); a1 += w.y * bfpair(c1.y);
        a2 += w.y * bfpair(c1.z); a3 += w.y * bfpair(c1.w);
        a0 += w.z * bfpair(c2.x); a1 += w.z * bfpair(c2.y);
        a2 += w.z * bfpair(c2.z); a3 += w.z * bfpair(c2.w);
        a0 += w.w * bfpair(c3.x); a1 += w.w * bfpair(c3.y);
        a2 += w.w * bfpair(c3.z); a3 += w.w * bfpair(c3.w);
        w = wn; c0 = n0; c1 = n1; c2 = n2; c3 = n3;
        __builtin_amdgcn_sched_barrier(0);   // fence: cap pipeline depth at 2
    }
    uint4 o;
    o.x = pk_bf16(a0.x, a0.y);
    o.y = pk_bf16(a1.x, a1.y);
    o.z = pk_bf16(a2.x, a2.y);
    o.w = pk_bf16(a3.x, a3.y);
    *(uint4*)(OUT + (size_t)m * 256 + l31 * 8) = o;
}

// ---------------------------------------------------------------------------
// Launch
// ---------------------------------------------------------------------------
extern "C" void kernel_launch(void* const* d_in, const int* in_sizes, int n_in,
                              void* d_out, int out_size, void* d_ws, size_t ws_size,
                              hipStream_t stream)
{
    const float* tgt        = (const float*)d_in[0];
    const float* qpos       = (const float*)d_in[1];
    const float* refp       = (const float*)d_in[2];
    const float* src        = (const float*)d_in[3];
    const float* sa_in_w    = (const float*)d_in[7];
    const float* sa_in_b    = (const float*)d_in[8];
    const float* sa_out_w   = (const float*)d_in[9];
    const float* sa_out_b   = (const float*)d_in[10];
    const float* norm2_w    = (const float*)d_in[11];
    const float* norm2_b    = (const float*)d_in[12];
    const float* ca_value_w = (const float*)d_in[13];
    const float* ca_value_b = (const float*)d_in[14];
    const float* ca_off_w   = (const float*)d_in[15];
    const float* ca_off_b   = (const float*)d_in[16];
    const float* ca_attw_w  = (const float*)d_in[17];
    const float* ca_attw_b  = (const float*)d_in[18];
    const float* ca_out_w   = (const float*)d_in[19];
    const float* ca_out_b   = (const float*)d_in[20];
    const float* norm1_w    = (const float*)d_in[21];
    const float* norm1_b    = (const float*)d_in[22];
    const float* lin1_w     = (const float*)d_in[23];
    const float* lin1_b     = (const float*)d_in[24];
    const float* lin2_w     = (const float*)d_in[25];
    const float* lin2_b     = (const float*)d_in[26];
    const float* norm3_w    = (const float*)d_in[27];
    const float* norm3_b    = (const float*)d_in[28];
    float* out = (float*)d_out;

    float* ws = (float*)d_ws;
    float* A  = ws;
    float* Bx = A  + 9830400;
    float* Cx = Bx + 4915200;
    float* Dx = Cx + 4915200;
    float* Ex = Dx + 4915200;
    float* Fx = Ex + 5570560;
    float* Gx = Fx + 19660800;

    unsigned short* qkB   = (unsigned short*)A;
    float*          t1    = A;
    float*          t2    = A;
    unsigned short* vB    = (unsigned short*)Bx;
    unsigned short* t1qB  = (unsigned short*)Bx;
    unsigned short* sampB = (unsigned short*)Bx;
    unsigned short* l2B   = (unsigned short*)Bx;
    unsigned short* aoB   = (unsigned short*)Cx;
    unsigned short* offB  = (unsigned short*)Cx;
    unsigned short* coB   = (unsigned short*)Cx;
    unsigned short* t2B   = (unsigned short*)Cx;
    unsigned short* soB   = (unsigned short*)Dx;
    float*          awL   = Dx;
    unsigned short* valB  = (unsigned short*)Ex;
    unsigned short* hidB  = (unsigned short*)Fx;
    unsigned short* wG    = (unsigned short*)Gx;

    // bf16 activation staging lives in Fx (dead before hidB is written at FFN1)
    unsigned short* qBa   = (unsigned short*)Fx;
    unsigned short* tgtBa = qBa + 9830400;
    unsigned short* srcBa = tgtBa + 9830400;

    unsigned short* wSAIN  = wG;            // 768*256
    unsigned short* wSAOUT = wG + 196608;   // 256*256
    unsigned short* wVAL   = wG + 262144;   // 256*256
    unsigned short* wOFF   = wG + 327680;   // 256*256
    unsigned short* wATT   = wG + 393216;   // 128*256
    unsigned short* wCAOUT = wG + 425984;   // 256*256
    unsigned short* wL1    = wG + 491520;   // 1024*256
    unsigned short* wL2    = wG + 753664;   // 256*1024

    dim3 blk(256);

    WcvtArgs wa;
    wa.src[0] = sa_in_w;    wa.dst[0] = wSAIN;  wa.n4[0] = 196608 / 4;
    wa.src[1] = sa_out_w;   wa.dst[1] = wSAOUT; wa.n4[1] = 65536 / 4;
    wa.src[2] = ca_value_w; wa.dst[2] = wVAL;   wa.n4[2] = 65536 / 4;
    wa.src[3] = ca_off_w;   wa.dst[3] = wOFF;   wa.n4[3] = 65536 / 4;
    wa.src[4] = ca_attw_w;  wa.dst[4] = wATT;   wa.n4[4] = 32768 / 4;
    wa.src[5] = ca_out_w;   wa.dst[5] = wCAOUT; wa.n4[5] = 65536 / 4;
    wa.src[6] = lin1_w;     wa.dst[6] = wL1;    wa.n4[6] = 262144 / 4;
    wa.src[7] = lin2_w;     wa.dst[7] = wL2;    wa.n4[7] = 262144 / 4;
    wcvt<<<512, blk, 0, stream>>>(wa);
    cvt_acts<<<2048, blk, 0, stream>>>(tgt, qpos, src, tgtBa, qBa, srcBa);

    // --- self-attention (+ value GEMM fused in) ---
    gemm_qkvval<<<dim3(8, 340), blk, 0, stream>>>(qBa, tgtBa, srcBa, wSAIN, sa_in_b,
                                                  qkB, vB, wVAL, ca_value_b, valB);
    attn16<<<2400, blk, 0, stream>>>(qkB, vB, aoB);
    gemm_std128<<<dim3(2, 300), blk, 0, stream>>>(aoB, wSAOUT, sa_out_b, soB, 1, 0, 256, 256);
    ln_res4<1, 1, 1><<<9600, blk, 0, stream>>>(soB, tgt, norm2_w, norm2_b, t1, t1qB, qpos);

    // --- MS deformable cross-attention ---
    gemm_offaw<<<dim3(3, 300), blk, 0, stream>>>(t1qB, wOFF, ca_off_b, offB, wATT, ca_attw_b, awL);
    ms_sample5<<<4800, blk, 0, stream>>>(valB, offB, awL, refp, sampB);
    gemm_std128<<<dim3(2, 300), blk, 0, stream>>>(sampB, wCAOUT, ca_out_b, coB, 1, 0, 256, 256);
    ln_res4<1, 1, 0><<<9600, blk, 0, stream>>>(coB, t1, norm1_w, norm1_b, t2, t2B, nullptr);

    // --- FFN ---
    gemm_std128<<<dim3(8, 300), blk, 0, stream>>>(t2B, wL1, lin1_b, hidB, 1, 1, 1024, 256);
    gemm_std128<<<dim3(2, 300), blk, 0, stream>>>(hidB, wL2, lin2_b, l2B, 1, 0, 256, 1024);
    ln_res4<1, 0, 0><<<9600, blk, 0, stream>>>(l2B, t2, norm3_w, norm3_b, out, nullptr, nullptr);
}

// Round 10
// 546.847 us; speedup vs baseline: 1.2110x; 1.1225x over previous
//
#include <hip/hip_runtime.h>

// ---------------------------------------------------------------------------
// D=256 HEADS=8 DH=32 LEVELS=4 POINTS=4 DFFN=1024 B=8 NQ=300 NC=16
// M1 = 38400, LEN_IN = 5440, value rows = 43520
// SPATIAL = (64,64),(32,32),(16,16),(8,8); level starts 0,4096,5120,5376
// ---------------------------------------------------------------------------

typedef __bf16 bf16x8 __attribute__((ext_vector_type(8)));
typedef float  f32x4  __attribute__((ext_vector_type(4)));
typedef float  f32x2  __attribute__((ext_vector_type(2)));

__device__ __forceinline__ unsigned pk_bf16(float lo, float hi)
{
    unsigned a = __float_as_uint(lo) + 0x8000u;
    unsigned b = __float_as_uint(hi) + 0x8000u;
    return __builtin_amdgcn_perm(b, a, 0x07060302u);
}
__device__ __forceinline__ unsigned short f2bf(float v)
{
    return (unsigned short)((__float_as_uint(v) + 0x8000u) >> 16);
}
__device__ __forceinline__ float bf_lo(unsigned u) { return __uint_as_float(u << 16); }
__device__ __forceinline__ float bf_hi(unsigned u) { return __uint_as_float(u & 0xffff0000u); }
__device__ __forceinline__ float bf1(unsigned short u) { return __uint_as_float((unsigned)u << 16); }
__device__ __forceinline__ f32x2 bfpair(unsigned u)
{
    f32x2 r;
    r.x = __uint_as_float(u << 16);
    r.y = __uint_as_float(u & 0xffff0000u);
    return r;
}

// XCD-aware chunked block swizzle (bijective for any nwg; m204 variant).
__device__ __forceinline__ int xcd_swz(int wgid, int nwg)
{
    const int q = nwg >> 3, r = nwg & 7;
    const int x = wgid & 7, k = wgid >> 3;
    return (x < r ? x * (q + 1) : r * (q + 1) + (x - r) * q) + k;
}

// async global->LDS, 16 B per lane. LDS dest must be wave-uniform base + lane*16.
__device__ __forceinline__ void gl_lds16(const unsigned short* g, unsigned short* l)
{
    __builtin_amdgcn_global_load_lds(
        (const __attribute__((address_space(1))) unsigned int*)g,
        (__attribute__((address_space(3))) unsigned int*)l,
        16, 0, 0);
}

// ---------------------------------------------------------------------------
// Weight pre-conversion fp32 -> bf16 (8 segments, one dispatch).
// ---------------------------------------------------------------------------
struct WcvtArgs {
    const float* src[8];
    unsigned short* dst[8];
    int n4[8];
};

__global__ __launch_bounds__(256) void wcvt(WcvtArgs a)
{
    const int gid = blockIdx.x * 256 + threadIdx.x;
    const int stride = gridDim.x * 256;
#pragma unroll
    for (int s = 0; s < 8; s++) {
        const float4* sp = (const float4*)a.src[s];
        uint2* dp = (uint2*)a.dst[s];
        for (int i = gid; i < a.n4[s]; i += stride) {
            float4 f = sp[i];
            uint2 o; o.x = pk_bf16(f.x, f.y); o.y = pk_bf16(f.z, f.w);
            dp[i] = o;
        }
    }
}

// ---------------------------------------------------------------------------
// Activation pre-conversion: tgtB = bf16(tgt), qB = bf16(tgt+qpos),
// srcB = bf16(src). Makes all GEMM A-operands bf16 (global_load_lds path).
// ---------------------------------------------------------------------------
__global__ __launch_bounds__(256) void cvt_acts(
    const float* __restrict__ tgt, const float* __restrict__ qpos,
    const float* __restrict__ src,
    unsigned short* __restrict__ tgtB, unsigned short* __restrict__ qB,
    unsigned short* __restrict__ srcB)
{
    const int gid = blockIdx.x * 256 + threadIdx.x;
    const int stride = gridDim.x * 256;
    for (int i = gid; i < 2457600; i += stride) {          // 38400*256/4
        float4 t = ((const float4*)tgt)[i];
        float4 p = ((const float4*)qpos)[i];
        uint2 a; a.x = pk_bf16(t.x, t.y); a.y = pk_bf16(t.z, t.w);
        ((uint2*)tgtB)[i] = a;
        uint2 b; b.x = pk_bf16(t.x + p.x, t.y + p.y);
        b.y = pk_bf16(t.z + p.z, t.w + p.w);
        ((uint2*)qB)[i] = b;
    }
    for (int i = gid; i < 2785280; i += stride) {          // 8*5440*256/4
        float4 s = ((const float4*)src)[i];
        uint2 c; c.x = pk_bf16(s.x, s.y); c.y = pk_bf16(s.z, s.w);
        ((uint2*)srcB)[i] = c;
    }
}

// ---------------------------------------------------------------------------
// GEMM core (m97 structure): 128x128 tile, BK=32, double-buffered LDS,
// global_load_lds width=16 staging, one barrier per K-step. 4 waves (2x2).
// Both-sides XOR slot-swizzle (slot ^= (row>>1)&3).
// A is bf16 [M,K]; W is bf16 [N,K]; C row-major [M,N].
// ---------------------------------------------------------------------------
__device__ __forceinline__ void gemm_core128(
    const unsigned short* __restrict__ Ab,
    const unsigned short* __restrict__ Wb, const float* __restrict__ bias,
    void* __restrict__ Cv, int outbf16, int relu,
    int row0, int col0, int N, int K,
    unsigned short (*sA)[128][32], unsigned short (*sB)[128][32])
{
    const int tid  = threadIdx.x;
    const int lane = tid & 63;
    const int wv   = tid >> 6;
    const int wr   = wv >> 1;
    const int wc   = wv & 1;
    const int lm   = lane & 15;
    const int q    = lane >> 4;
    const int q4   = q << 2;

    const int tr = tid >> 2;
    const int ts = tid & 3;

    f32x4 acc[4][4] = {};
    const int iters = K >> 5;

    auto stage = [&](int buf, int k) {
#pragma unroll
        for (int r = 0; r < 2; ++r) {
            const int row = r * 64 + tr;
            const int sw  = ts ^ ((row >> 1) & 3);
            gl_lds16(Ab + (size_t)(row0 + row) * K + k + sw * 8,
                     &sA[buf][0][0] + (size_t)(r * 256 + tid) * 8);
            gl_lds16(Wb + (size_t)(col0 + row) * K + k + sw * 8,
                     &sB[buf][0][0] + (size_t)(r * 256 + tid) * 8);
        }
    };

    stage(0, 0);

    for (int it = 0; it < iters; ++it) {
        __syncthreads();
        const int buf = it & 1;
        if (it + 1 < iters) stage(buf ^ 1, (it + 1) << 5);

        bf16x8 av[4], bv[4];
#pragma unroll
        for (int mi = 0; mi < 4; mi++) {
            const int row = wr * 64 + mi * 16 + lm;
            av[mi] = *(const bf16x8*)&sA[buf][row][(q ^ ((row >> 1) & 3)) * 8];
        }
#pragma unroll
        for (int ni = 0; ni < 4; ni++) {
            const int row = wc * 64 + ni * 16 + lm;
            bv[ni] = *(const bf16x8*)&sB[buf][row][(q ^ ((row >> 1) & 3)) * 8];
        }
#pragma unroll
        for (int mi = 0; mi < 4; mi++)
#pragma unroll
            for (int ni = 0; ni < 4; ni++)
                acc[mi][ni] = __builtin_amdgcn_mfma_f32_16x16x32_bf16(
                    av[mi], bv[ni], acc[mi][ni], 0, 0, 0);
    }

#pragma unroll
    for (int ni = 0; ni < 4; ni++) {
        const int col = col0 + wc * 64 + ni * 16 + lm;
        const float bsv = bias[col];
#pragma unroll
        for (int mi = 0; mi < 4; mi++) {
            const int rowb = row0 + wr * 64 + mi * 16 + q4;
#pragma unroll
            for (int rr = 0; rr < 4; rr++) {
                float v = acc[mi][ni][rr] + bsv;
                if (relu) v = fmaxf(v, 0.f);
                if (outbf16)
                    ((unsigned short*)Cv)[(size_t)(rowb + rr) * N + col] = f2bf(v);
                else
                    ((float*)Cv)[(size_t)(rowb + rr) * N + col] = v;
            }
        }
    }
}

__global__ __launch_bounds__(256) void gemm_std128(
    const unsigned short* __restrict__ Ab,
    const unsigned short* __restrict__ Wb, const float* __restrict__ bias,
    void* __restrict__ Cv, int outbf16, int relu, int N, int K)
{
    __shared__ unsigned short sA[2][128][32];
    __shared__ unsigned short sB[2][128][32];
    const int nwg = gridDim.x * gridDim.y;
    const int w = xcd_swz(blockIdx.x + gridDim.x * blockIdx.y, nwg);
    const int x = w % gridDim.x, y = w / gridDim.x;
    gemm_core128(Ab, Wb, bias, Cv, outbf16, relu,
                 y * 128, x * 128, N, K, sA, sB);
}

// ---------------------------------------------------------------------------
// GEMM 64x128 tile (M-split) for small-grid N=256 GEMMs: doubles block count
// (600 -> 1200, 2.3 -> ~4.7 blocks/CU) for latency hiding. LDS 24 KB ->
// 6 blocks/CU cap. 4 waves, each 32x64 (2x4 frags, acc 32 VGPR). Same
// m97 staging + both-sides XOR slot-swizzle as gemm_core128.
// ---------------------------------------------------------------------------
__global__ __launch_bounds__(256) void gemm_m64(
    const unsigned short* __restrict__ Ab,
    const unsigned short* __restrict__ Wb, const float* __restrict__ bias,
    void* __restrict__ Cv, int outbf16, int relu, int N, int K)
{
    __shared__ unsigned short sA[2][64][32];
    __shared__ unsigned short sB[2][128][32];

    const int nwg = gridDim.x * gridDim.y;
    const int w = xcd_swz(blockIdx.x + gridDim.x * blockIdx.y, nwg);
    const int x = w % gridDim.x, y = w / gridDim.x;
    const int row0 = y * 64, col0 = x * 128;

    const int tid  = threadIdx.x;
    const int lane = tid & 63;
    const int wv   = tid >> 6;
    const int wr   = wv >> 1;          // 0..1: 32-row group
    const int wc   = wv & 1;           // 0..1: 64-col group
    const int lm   = lane & 15;
    const int q    = lane >> 4;
    const int q4   = q << 2;

    const int tr = tid >> 2;           // 0..63
    const int ts = tid & 3;

    f32x4 acc[2][4] = {};
    const int iters = K >> 5;

    auto stage = [&](int buf, int k) {
        {
            const int row = tr;
            const int sw  = ts ^ ((row >> 1) & 3);
            gl_lds16(Ab + (size_t)(row0 + row) * K + k + sw * 8,
                     &sA[buf][0][0] + (size_t)tid * 8);
        }
#pragma unroll
        for (int r = 0; r < 2; ++r) {
            const int row = r * 64 + tr;
            const int sw  = ts ^ ((row >> 1) & 3);
            gl_lds16(Wb + (size_t)(col0 + row) * K + k + sw * 8,
                     &sB[buf][0][0] + (size_t)(r * 256 + tid) * 8);
        }
    };

    stage(0, 0);

    for (int it = 0; it < iters; ++it) {
        __syncthreads();
        const int buf = it & 1;
        if (it + 1 < iters) stage(buf ^ 1, (it + 1) << 5);

        bf16x8 av[2], bv[4];
#pragma unroll
        for (int mi = 0; mi < 2; mi++) {
            const int row = wr * 32 + mi * 16 + lm;
            av[mi] = *(const bf16x8*)&sA[buf][row][(q ^ ((row >> 1) & 3)) * 8];
        }
#pragma unroll
        for (int ni = 0; ni < 4; ni++) {
            const int row = wc * 64 + ni * 16 + lm;
            bv[ni] = *(const bf16x8*)&sB[buf][row][(q ^ ((row >> 1) & 3)) * 8];
        }
#pragma unroll
        for (int mi = 0; mi < 2; mi++)
#pragma unroll
            for (int ni = 0; ni < 4; ni++)
                acc[mi][ni] = __builtin_amdgcn_mfma_f32_16x16x32_bf16(
                    av[mi], bv[ni], acc[mi][ni], 0, 0, 0);
    }

#pragma unroll
    for (int ni = 0; ni < 4; ni++) {
        const int col = col0 + wc * 64 + ni * 16 + lm;
        const float bsv = bias[col];
#pragma unroll
        for (int mi = 0; mi < 2; mi++) {
            const int rowb = row0 + wr * 32 + mi * 16 + q4;
#pragma unroll
            for (int rr = 0; rr < 4; rr++) {
                float v = acc[mi][ni][rr] + bsv;
                if (relu) v = fmaxf(v, 0.f);
                if (outbf16)
                    ((unsigned short*)Cv)[(size_t)(rowb + rr) * N + col] = f2bf(v);
                else
                    ((float*)Cv)[(size_t)(rowb + rr) * N + col] = v;
            }
        }
    }
}

// fused: qk = qB@Wqk^T (N=512, x=0..3), v = tgtB@Wv^T (x=4..5),
// value = srcB@Wval^T over 43520 rows (x=6..7). grid (8, 340).
__global__ __launch_bounds__(256) void gemm_qkvval(
    const unsigned short* __restrict__ qB, const unsigned short* __restrict__ tgtB,
    const unsigned short* __restrict__ srcB,
    const unsigned short* __restrict__ Wsa, const float* __restrict__ bsa,
    unsigned short* __restrict__ qkB, unsigned short* __restrict__ vB,
    const unsigned short* __restrict__ Wval, const float* __restrict__ bval,
    unsigned short* __restrict__ valB)
{
    __shared__ unsigned short sA[2][128][32];
    __shared__ unsigned short sB[2][128][32];
    const int w = xcd_swz(blockIdx.x + 8 * blockIdx.y, 2720);
    const int x = w & 7, y = w >> 3;
    if (x < 4) {
        if (y >= 300) return;
        gemm_core128(qB, Wsa, bsa, qkB, 1, 0, y * 128, x * 128, 512, 256, sA, sB);
    } else if (x < 6) {
        if (y >= 300) return;
        gemm_core128(tgtB, Wsa + 512 * 256, bsa + 512, vB, 1, 0,
                     y * 128, (x - 4) * 128, 256, 256, sA, sB);
    } else {
        gemm_core128(srcB, Wval, bval, valB, 1, 0,
                     y * 128, (x - 6) * 128, 256, 256, sA, sB);
    }
}

// fused: off (N=256, x=0..1, bf16 out) and attw logits (N=128, x=2, fp32 out)
__global__ __launch_bounds__(256) void gemm_offaw(
    const unsigned short* __restrict__ X,
    const unsigned short* __restrict__ Woff, const float* __restrict__ boff,
    unsigned short* __restrict__ offB,
    const unsigned short* __restrict__ Watt, const float* __restrict__ batt,
    float* __restrict__ awL)
{
    __shared__ unsigned short sA[2][128][32];
    __shared__ unsigned short sB[2][128][32];
    const int w = xcd_swz(blockIdx.x + 3 * blockIdx.y, 900);
    const int x = w % 3, y = w / 3;
    if (x >= 2)
        gemm_core128(X, Watt, batt, awL, 0, 0,
                     y * 128, 0, 128, 256, sA, sB);
    else
        gemm_core128(X, Woff, boff, offB, 1, 0,
                     y * 128, x * 128, 256, 256, sA, sB);
}

// ---------------------------------------------------------------------------
// Self-attention over NC=16 groups; bf16 LDS, padded rows (conflict-free).
// ---------------------------------------------------------------------------
__global__ __launch_bounds__(256) void attn16(
    const unsigned short* __restrict__ QK, const unsigned short* __restrict__ V,
    unsigned short* __restrict__ O)
{
    __shared__ unsigned short sqk[16][520];
    __shared__ unsigned short sv[16][264];
    __shared__ float sp[128][17];

    const int g = blockIdx.x;
    const int tid = threadIdx.x;

    const uint4* qg = (const uint4*)(QK + (size_t)g * 8192);
    for (int i = tid; i < 1024; i += 256)
        *(uint4*)&sqk[i >> 6][(i & 63) * 8] = qg[i];
    const uint4* vg = (const uint4*)(V + (size_t)g * 4096);
    for (int i = tid; i < 512; i += 256)
        *(uint4*)&sv[i >> 5][(i & 31) * 8] = vg[i];
    __syncthreads();

#pragma unroll 2
    for (int s = tid; s < 2048; s += 256) {
        const int h = s >> 8, qi = (s >> 4) & 15, kj = s & 15;
        const uint4* qp = (const uint4*)&sqk[qi][h * 32];
        const uint4* kp = (const uint4*)&sqk[kj][256 + h * 32];
        float acc = 0.f;
#pragma unroll
        for (int c = 0; c < 4; c++) {
            uint4 qu = qp[c];
            uint4 ku = kp[c];
            acc += bf_lo(qu.x) * bf_lo(ku.x) + bf_hi(qu.x) * bf_hi(ku.x)
                 + bf_lo(qu.y) * bf_lo(ku.y) + bf_hi(qu.y) * bf_hi(ku.y)
                 + bf_lo(qu.z) * bf_lo(ku.z) + bf_hi(qu.z) * bf_hi(ku.z)
                 + bf_lo(qu.w) * bf_lo(ku.w) + bf_hi(qu.w) * bf_hi(ku.w);
        }
        sp[s >> 4][s & 15] = acc * 0.17677669529663687f;
    }
    __syncthreads();

    if (tid < 128) {
        float* row = sp[tid];
        float mx = row[0];
#pragma unroll
        for (int j = 1; j < 16; j++) mx = fmaxf(mx, row[j]);
        float sum = 0.f;
#pragma unroll
        for (int j = 0; j < 16; j++) { float e = __expf(row[j] - mx); row[j] = e; sum += e; }
        float inv = 1.f / sum;
#pragma unroll
        for (int j = 0; j < 16; j++) row[j] *= inv;
    }
    __syncthreads();

    uint2* og = (uint2*)(O + (size_t)g * 4096);
    for (int o = tid; o < 1024; o += 256) {
        const int qi = o >> 6, cq = o & 63, h = cq >> 3;
        const float* pr = sp[h * 16 + qi];
        float a0 = 0.f, a1 = 0.f, a2 = 0.f, a3 = 0.f;
#pragma unroll
        for (int j = 0; j < 16; j++) {
            uint2 u = *(const uint2*)&sv[j][cq * 4];
            float p = pr[j];
            a0 += p * bf_lo(u.x); a1 += p * bf_hi(u.x);
            a2 += p * bf_lo(u.y); a3 += p * bf_hi(u.y);
        }
        uint2 r; r.x = pk_bf16(a0, a1); r.y = pk_bf16(a2, a3);
        og[o] = r;
    }
}

// ---------------------------------------------------------------------------
// Residual + LN, wave-per-row (4 rows/block), butterfly shuffles, no LDS.
// ---------------------------------------------------------------------------
template <int XBF16, int WRITE2, int ADDQ>
__global__ __launch_bounds__(256) void ln_res4(
    const void* __restrict__ Xv, const float* __restrict__ R,
    const float* __restrict__ w, const float* __restrict__ b,
    float* __restrict__ out, unsigned short* __restrict__ out2,
    const float* __restrict__ qpos)
{
    const int row = blockIdx.x * 4 + (threadIdx.x >> 6);
    const int lane = threadIdx.x & 63;
    const size_t base = (size_t)row * 256 + lane * 4;

    float x0, x1, x2, x3;
    if (XBF16) {
        uint2 u = *(const uint2*)((const unsigned short*)Xv + base);
        x0 = bf_lo(u.x); x1 = bf_hi(u.x); x2 = bf_lo(u.y); x3 = bf_hi(u.y);
    } else {
        float4 f = *(const float4*)((const float*)Xv + base);
        x0 = f.x; x1 = f.y; x2 = f.z; x3 = f.w;
    }
    float4 r4 = *(const float4*)&R[base];
    float v0 = x0 + r4.x, v1 = x1 + r4.y, v2 = x2 + r4.z, v3 = x3 + r4.w;

    float s = v0 + v1 + v2 + v3;
#pragma unroll
    for (int o = 32; o > 0; o >>= 1) s += __shfl_xor(s, o);
    const float mean = s * (1.f / 256.f);
    const float d0 = v0 - mean, d1 = v1 - mean, d2 = v2 - mean, d3 = v3 - mean;
    float qv = d0 * d0 + d1 * d1 + d2 * d2 + d3 * d3;
#pragma unroll
    for (int o = 32; o > 0; o >>= 1) qv += __shfl_xor(qv, o);
    const float rs = rsqrtf(qv * (1.f / 256.f) + 1e-5f);

    float4 w4 = *(const float4*)&w[lane * 4];
    float4 b4 = *(const float4*)&b[lane * 4];
    float y0 = d0 * rs * w4.x + b4.x;
    float y1 = d1 * rs * w4.y + b4.y;
    float y2 = d2 * rs * w4.z + b4.z;
    float y3 = d3 * rs * w4.w + b4.w;

    float4 o4; o4.x = y0; o4.y = y1; o4.z = y2; o4.w = y3;
    *(float4*)&out[base] = o4;
    if (WRITE2) {
        float z0 = y0, z1 = y1, z2 = y2, z3 = y3;
        if (ADDQ) {
            float4 qp4 = *(const float4*)&qpos[base];
            z0 += qp4.x; z1 += qp4.y; z2 += qp4.z; z3 += qp4.w;
        }
        uint2 u; u.x = pk_bf16(z0, z1); u.y = pk_bf16(z2, z3);
        *(uint2*)(out2 + base) = u;
    }
}

// ---------------------------------------------------------------------------
// MS-deformable sampling (R4-proven v3): 256 threads/block, 8 queries/block,
// 2 q/wave (32 lanes/query; lane owns a 16-B slice of one head). 4800 blocks
// -> XCD chunk = exactly one batch per XCD (2.79 MB value slice L2-resident).
// Plain gather loop (VGPR 40, occ ~50%, 73.5 µs) — both software-pipelining
// attempts (R5 unfenced, R8 sched_barrier-fenced) blew VGPR to 244-256 and
// regressed to 140 µs; this loop is at its structural latency floor.
// ---------------------------------------------------------------------------
__global__ __launch_bounds__(256) void ms_sample3(
    const unsigned short* __restrict__ VAL, const unsigned short* __restrict__ OFF,
    const float* __restrict__ AWL, const float* __restrict__ REF,
    unsigned short* __restrict__ OUT)
{
    __shared__ char smem[24576];
    unsigned short* soff = (unsigned short*)smem;            // [8][256]   (A)
    float*          saw  = (float*)(smem + 4096);            // [8][128]   (A)
    float*          sref = (float*)(smem + 8192);            // [8][8]     (A)
    float*          swt  = (float*)smem;                     // [8][16][8][4]   (B)
    unsigned short* sidx = (unsigned short*)(smem + 16384);  // [8][16][8][4]   (B)

    const int wblk = xcd_swz(blockIdx.x, 4800);
    const int m0 = wblk * 8, tid = threadIdx.x;

    // --- phase 0: load offsets / logits / refs (region A) ---
    ((uint4*)soff)[tid]  = ((const uint4*)(OFF + (size_t)m0 * 256))[tid];
    ((float4*)saw)[tid]  = ((const float4*)(AWL + (size_t)m0 * 128))[tid];
    if (tid < 64) sref[tid] = REF[(size_t)m0 * 8 + tid];
    __syncthreads();

    // --- phase 1: softmax over 16 logits per (q,h): 64 rows, all threads ---
    {
        const int row = tid >> 2, part = tid & 3;     // row = q*8+h
        float4 lg = *(float4*)&saw[row * 16 + part * 4];
        float mx = fmaxf(fmaxf(lg.x, lg.y), fmaxf(lg.z, lg.w));
        mx = fmaxf(mx, __shfl_xor(mx, 1));
        mx = fmaxf(mx, __shfl_xor(mx, 2));
        float e0 = __expf(lg.x - mx), e1 = __expf(lg.y - mx);
        float e2 = __expf(lg.z - mx), e3 = __expf(lg.w - mx);
        float s = e0 + e1 + e2 + e3;
        s += __shfl_xor(s, 1);
        s += __shfl_xor(s, 2);
        const float inv = 1.f / s;
        float4 pr; pr.x = e0 * inv; pr.y = e1 * inv; pr.z = e2 * inv; pr.w = e3 * inv;
        *(float4*)&saw[row * 16 + part * 4] = pr;
    }
    __syncthreads();

    // --- phase 2: decode 1024 items (4/thread) into registers ---
    float4  w4r[4];
    ushort4 rr4[4];
#pragma unroll
    for (int k = 0; k < 4; k++) {
        const int c = tid + k * 256;
        const int qi = c >> 7, h = c & 7, j = (c >> 3) & 15;
        const int l = j >> 2, p = j & 3;
        const int Wl = 64 >> l;
        const int st = (l == 0) ? 0 : (l == 1) ? 4096 : (l == 2) ? 5120 : 5376;
        const float fS = (float)Wl;
        const unsigned short* ob = &soff[qi * 256 + h * 32 + l * 8 + p * 2];
        const float x = sref[qi * 8 + l * 2 + 0] * fS + bf1(ob[0]) - 0.5f;
        const float y = sref[qi * 8 + l * 2 + 1] * fS + bf1(ob[1]) - 0.5f;
        const float x0f = floorf(x), y0f = floorf(y);
        const float fx = x - x0f, fy = y - y0f;
        const int x0 = (int)x0f, y0 = (int)y0f;
        const int x1 = x0 + 1, y1 = y0 + 1;
        const float vx0 = (x0 >= 0 && x0 < Wl) ? 1.f : 0.f;
        const float vx1 = (x1 >= 0 && x1 < Wl) ? 1.f : 0.f;
        const float vy0 = (y0 >= 0 && y0 < Wl) ? 1.f : 0.f;
        const float vy1 = (y1 >= 0 && y1 < Wl) ? 1.f : 0.f;
        const int cx0 = min(max(x0, 0), Wl - 1);
        const int cx1 = min(max(x1, 0), Wl - 1);
        const int cy0 = min(max(y0, 0), Wl - 1);
        const int cy1 = min(max(y1, 0), Wl - 1);
        const float aw = saw[qi * 128 + h * 16 + j];
        w4r[k].x = (1.f - fx) * (1.f - fy) * vx0 * vy0 * aw;
        w4r[k].y = fx * (1.f - fy) * vx1 * vy0 * aw;
        w4r[k].z = (1.f - fx) * fy * vx0 * vy1 * aw;
        w4r[k].w = fx * fy * vx1 * vy1 * aw;
        rr4[k].x = (unsigned short)(st + cy0 * Wl + cx0);
        rr4[k].y = (unsigned short)(st + cy0 * Wl + cx1);
        rr4[k].z = (unsigned short)(st + cy1 * Wl + cx0);
        rr4[k].w = (unsigned short)(st + cy1 * Wl + cx1);
    }
    __syncthreads();   // region A dead; write region B

#pragma unroll
    for (int k = 0; k < 4; k++) {
        const int c = tid + k * 256;
        const int qi = c >> 7, h = c & 7, j = (c >> 3) & 15;
        *(float4*)&swt[((qi * 16 + j) * 8 + h) * 4]   = w4r[k];
        *(ushort4*)&sidx[((qi * 16 + j) * 8 + h) * 4] = rr4[k];
    }
    __syncthreads();

    // --- phase 3: gather + weighted accumulate (16 B / lane) ---
    const int qi = tid >> 5;                // query within block (2/wave)
    const int l31 = tid & 31;               // lane within query
    const int h = l31 >> 2;                 // head
    const unsigned loff = (unsigned)l31 * 16;
    const int m = m0 + qi;
    const char* vbase = (const char*)VAL + (size_t)(m0 / 4800) * 5440 * 512;

    f32x2 a0 = {0.f, 0.f}, a1 = {0.f, 0.f}, a2 = {0.f, 0.f}, a3 = {0.f, 0.f};
#pragma unroll 8
    for (int j = 0; j < 16; j++) {
        const float4  w  = *(const float4*)&swt[((qi * 16 + j) * 8 + h) * 4];
        const ushort4 rw = *(const ushort4*)&sidx[((qi * 16 + j) * 8 + h) * 4];
        const uint4 c0 = *(const uint4*)(vbase + (((unsigned)rw.x << 9) + loff));
        const uint4 c1 = *(const uint4*)(vbase + (((unsigned)rw.y << 9) + loff));
        const uint4 c2 = *(const uint4*)(vbase + (((unsigned)rw.z << 9) + loff));
        const uint4 c3 = *(const uint4*)(vbase + (((unsigned)rw.w << 9) + loff));
        a0 += w.x * bfpair(c0.x); a1 += w.x * bfpair(c0.y);
        a2 += w.x * bfpair(c0.z); a3 += w.x * bfpair(c0.w);
        a0 += w.y * bfpair(c1.x); a1 += w.y * bfpair(c1.y);
        a2 += w.y * bfpair(c1.z); a3 += w.y * bfpair(c1.w);
        a0 += w.z * bfpair(c2.x); a1 += w.z * bfpair(c2.y);
        a2 += w.z * bfpair(c2.z); a3 += w.z * bfpair(c2.w);
        a0 += w.w * bfpair(c3.x); a1 += w.w * bfpair(c3.y);
        a2 += w.w * bfpair(c3.z); a3 += w.w * bfpair(c3.w);
    }
    uint4 o;
    o.x = pk_bf16(a0.x, a0.y);
    o.y = pk_bf16(a1.x, a1.y);
    o.z = pk_bf16(a2.x, a2.y);
    o.w = pk_bf16(a3.x, a3.y);
    *(uint4*)(OUT + (size_t)m * 256 + l31 * 8) = o;
}

// ---------------------------------------------------------------------------
// Launch
// ---------------------------------------------------------------------------
extern "C" void kernel_launch(void* const* d_in, const int* in_sizes, int n_in,
                              void* d_out, int out_size, void* d_ws, size_t ws_size,
                              hipStream_t stream)
{
    const float* tgt        = (const float*)d_in[0];
    const float* qpos       = (const float*)d_in[1];
    const float* refp       = (const float*)d_in[2];
    const float* src        = (const float*)d_in[3];
    const float* sa_in_w    = (const float*)d_in[7];
    const float* sa_in_b    = (const float*)d_in[8];
    const float* sa_out_w   = (const float*)d_in[9];
    const float* sa_out_b   = (const float*)d_in[10];
    const float* norm2_w    = (const float*)d_in[11];
    const float* norm2_b    = (const float*)d_in[12];
    const float* ca_value_w = (const float*)d_in[13];
    const float* ca_value_b = (const float*)d_in[14];
    const float* ca_off_w   = (const float*)d_in[15];
    const float* ca_off_b   = (const float*)d_in[16];
    const float* ca_attw_w  = (const float*)d_in[17];
    const float* ca_attw_b  = (const float*)d_in[18];
    const float* ca_out_w   = (const float*)d_in[19];
    const float* ca_out_b   = (const float*)d_in[20];
    const float* norm1_w    = (const float*)d_in[21];
    const float* norm1_b    = (const float*)d_in[22];
    const float* lin1_w     = (const float*)d_in[23];
    const float* lin1_b     = (const float*)d_in[24];
    const float* lin2_w     = (const float*)d_in[25];
    const float* lin2_b     = (const float*)d_in[26];
    const float* norm3_w    = (const float*)d_in[27];
    const float* norm3_b    = (const float*)d_in[28];
    float* out = (float*)d_out;

    float* ws = (float*)d_ws;
    float* A  = ws;
    float* Bx = A  + 9830400;
    float* Cx = Bx + 4915200;
    float* Dx = Cx + 4915200;
    float* Ex = Dx + 4915200;
    float* Fx = Ex + 5570560;
    float* Gx = Fx + 19660800;

    unsigned short* qkB   = (unsigned short*)A;
    float*          t1    = A;
    float*          t2    = A;
    unsigned short* vB    = (unsigned short*)Bx;
    unsigned short* t1qB  = (unsigned short*)Bx;
    unsigned short* sampB = (unsigned short*)Bx;
    unsigned short* l2B   = (unsigned short*)Bx;
    unsigned short* aoB   = (unsigned short*)Cx;
    unsigned short* offB  = (unsigned short*)Cx;
    unsigned short* coB   = (unsigned short*)Cx;
    unsigned short* t2B   = (unsigned short*)Cx;
    unsigned short* soB   = (unsigned short*)Dx;
    float*          awL   = Dx;
    unsigned short* valB  = (unsigned short*)Ex;
    unsigned short* hidB  = (unsigned short*)Fx;
    unsigned short* wG    = (unsigned short*)Gx;

    // bf16 activation staging lives in Fx (dead before hidB is written at FFN1)
    unsigned short* qBa   = (unsigned short*)Fx;
    unsigned short* tgtBa = qBa + 9830400;
    unsigned short* srcBa = tgtBa + 9830400;

    unsigned short* wSAIN  = wG;            // 768*256
    unsigned short* wSAOUT = wG + 196608;   // 256*256
    unsigned short* wVAL   = wG + 262144;   // 256*256
    unsigned short* wOFF   = wG + 327680;   // 256*256
    unsigned short* wATT   = wG + 393216;   // 128*256
    unsigned short* wCAOUT = wG + 425984;   // 256*256
    unsigned short* wL1    = wG + 491520;   // 1024*256
    unsigned short* wL2    = wG + 753664;   // 256*1024

    dim3 blk(256);

    WcvtArgs wa;
    wa.src[0] = sa_in_w;    wa.dst[0] = wSAIN;  wa.n4[0] = 196608 / 4;
    wa.src[1] = sa_out_w;   wa.dst[1] = wSAOUT; wa.n4[1] = 65536 / 4;
    wa.src[2] = ca_value_w; wa.dst[2] = wVAL;   wa.n4[2] = 65536 / 4;
    wa.src[3] = ca_off_w;   wa.dst[3] = wOFF;   wa.n4[3] = 65536 / 4;
    wa.src[4] = ca_attw_w;  wa.dst[4] = wATT;   wa.n4[4] = 32768 / 4;
    wa.src[5] = ca_out_w;   wa.dst[5] = wCAOUT; wa.n4[5] = 65536 / 4;
    wa.src[6] = lin1_w;     wa.dst[6] = wL1;    wa.n4[6] = 262144 / 4;
    wa.src[7] = lin2_w;     wa.dst[7] = wL2;    wa.n4[7] = 262144 / 4;
    wcvt<<<512, blk, 0, stream>>>(wa);
    cvt_acts<<<2048, blk, 0, stream>>>(tgt, qpos, src, tgtBa, qBa, srcBa);

    // --- self-attention (+ value GEMM fused in) ---
    gemm_qkvval<<<dim3(8, 340), blk, 0, stream>>>(qBa, tgtBa, srcBa, wSAIN, sa_in_b,
                                                  qkB, vB, wVAL, ca_value_b, valB);
    attn16<<<2400, blk, 0, stream>>>(qkB, vB, aoB);
    gemm_m64<<<dim3(2, 600), blk, 0, stream>>>(aoB, wSAOUT, sa_out_b, soB, 1, 0, 256, 256);
    ln_res4<1, 1, 1><<<9600, blk, 0, stream>>>(soB, tgt, norm2_w, norm2_b, t1, t1qB, qpos);

    // --- MS deformable cross-attention ---
    gemm_offaw<<<dim3(3, 300), blk, 0, stream>>>(t1qB, wOFF, ca_off_b, offB, wATT, ca_attw_b, awL);
    ms_sample3<<<4800, blk, 0, stream>>>(valB, offB, awL, refp, sampB);
    gemm_m64<<<dim3(2, 600), blk, 0, stream>>>(sampB, wCAOUT, ca_out_b, coB, 1, 0, 256, 256);
    ln_res4<1, 1, 0><<<9600, blk, 0, stream>>>(coB, t1, norm1_w, norm1_b, t2, t2B, nullptr);

    // --- FFN ---
    gemm_std128<<<dim3(8, 300), blk, 0, stream>>>(t2B, wL1, lin1_b, hidB, 1, 1, 1024, 256);
    gemm_m64<<<dim3(2, 600), blk, 0, stream>>>(hidB, wL2, lin2_b, l2B, 1, 0, 256, 1024);
    ln_res4<1, 0, 0><<<9600, blk, 0, stream>>>(l2B, t2, norm3_w, norm3_b, out, nullptr, nullptr);
}

// Round 11
// 536.850 us; speedup vs baseline: 1.2335x; 1.0186x over previous
//
#include <hip/hip_runtime.h>

// ---------------------------------------------------------------------------
// D=256 HEADS=8 DH=32 LEVELS=4 POINTS=4 DFFN=1024 B=8 NQ=300 NC=16
// M1 = 38400, LEN_IN = 5440, value rows = 43520
// SPATIAL = (64,64),(32,32),(16,16),(8,8); level starts 0,4096,5120,5376
// ---------------------------------------------------------------------------

typedef __bf16 bf16x8 __attribute__((ext_vector_type(8)));
typedef float  f32x4  __attribute__((ext_vector_type(4)));
typedef float  f32x2  __attribute__((ext_vector_type(2)));

__device__ __forceinline__ unsigned pk_bf16(float lo, float hi)
{
    unsigned a = __float_as_uint(lo) + 0x8000u;
    unsigned b = __float_as_uint(hi) + 0x8000u;
    return __builtin_amdgcn_perm(b, a, 0x07060302u);
}
__device__ __forceinline__ unsigned short f2bf(float v)
{
    return (unsigned short)((__float_as_uint(v) + 0x8000u) >> 16);
}
__device__ __forceinline__ float bf_lo(unsigned u) { return __uint_as_float(u << 16); }
__device__ __forceinline__ float bf_hi(unsigned u) { return __uint_as_float(u & 0xffff0000u); }
__device__ __forceinline__ float bf1(unsigned short u) { return __uint_as_float((unsigned)u << 16); }
__device__ __forceinline__ f32x2 bfpair(unsigned u)
{
    f32x2 r;
    r.x = __uint_as_float(u << 16);
    r.y = __uint_as_float(u & 0xffff0000u);
    return r;
}

// XCD-aware chunked block swizzle (bijective for any nwg; m204 variant).
__device__ __forceinline__ int xcd_swz(int wgid, int nwg)
{
    const int q = nwg >> 3, r = nwg & 7;
    const int x = wgid & 7, k = wgid >> 3;
    return (x < r ? x * (q + 1) : r * (q + 1) + (x - r) * q) + k;
}

// async global->LDS, 16 B per lane. LDS dest must be wave-uniform base + lane*16.
__device__ __forceinline__ void gl_lds16(const unsigned short* g, unsigned short* l)
{
    __builtin_amdgcn_global_load_lds(
        (const __attribute__((address_space(1))) unsigned int*)g,
        (__attribute__((address_space(3))) unsigned int*)l,
        16, 0, 0);
}

// ---------------------------------------------------------------------------
// Combined pre-conversion (one dispatch): weights fp32->bf16 (8 segments) +
// activations tgtB = bf16(tgt), qB = bf16(tgt+qpos), srcB = bf16(src).
// All outputs disjoint; grid-stride; BW-bound.
// ---------------------------------------------------------------------------
struct CvtArgs {
    const float* wsrc[8];
    unsigned short* wdst[8];
    int n4[8];
    const float* tgt;
    const float* qpos;
    const float* src;
    unsigned short* tgtB;
    unsigned short* qB;
    unsigned short* srcB;
};

__global__ __launch_bounds__(256) void cvt_all(CvtArgs a)
{
    const int gid = blockIdx.x * 256 + threadIdx.x;
    const int stride = gridDim.x * 256;

    for (int i = gid; i < 2457600; i += stride) {          // 38400*256/4
        float4 t = ((const float4*)a.tgt)[i];
        float4 p = ((const float4*)a.qpos)[i];
        uint2 o1; o1.x = pk_bf16(t.x, t.y); o1.y = pk_bf16(t.z, t.w);
        ((uint2*)a.tgtB)[i] = o1;
        uint2 o2; o2.x = pk_bf16(t.x + p.x, t.y + p.y);
        o2.y = pk_bf16(t.z + p.z, t.w + p.w);
        ((uint2*)a.qB)[i] = o2;
    }
    for (int i = gid; i < 2785280; i += stride) {          // 8*5440*256/4
        float4 s = ((const float4*)a.src)[i];
        uint2 c; c.x = pk_bf16(s.x, s.y); c.y = pk_bf16(s.z, s.w);
        ((uint2*)a.srcB)[i] = c;
    }
#pragma unroll
    for (int s = 0; s < 8; s++) {
        const float4* sp = (const float4*)a.wsrc[s];
        uint2* dp = (uint2*)a.wdst[s];
        for (int i = gid; i < a.n4[s]; i += stride) {
            float4 f = sp[i];
            uint2 o; o.x = pk_bf16(f.x, f.y); o.y = pk_bf16(f.z, f.w);
            dp[i] = o;
        }
    }
}

// ---------------------------------------------------------------------------
// GEMM core (m97 structure): 128x128 tile, BK=32, double-buffered LDS,
// global_load_lds width=16 staging, one barrier per K-step. 4 waves (2x2).
// Both-sides XOR slot-swizzle (slot ^= (row>>1)&3).
// A is bf16 [M,K]; W is bf16 [N,K]; C row-major [M,N].
// ---------------------------------------------------------------------------
__device__ __forceinline__ void gemm_core128(
    const unsigned short* __restrict__ Ab,
    const unsigned short* __restrict__ Wb, const float* __restrict__ bias,
    void* __restrict__ Cv, int outbf16, int relu,
    int row0, int col0, int N, int K,
    unsigned short (*sA)[128][32], unsigned short (*sB)[128][32])
{
    const int tid  = threadIdx.x;
    const int lane = tid & 63;
    const int wv   = tid >> 6;
    const int wr   = wv >> 1;
    const int wc   = wv & 1;
    const int lm   = lane & 15;
    const int q    = lane >> 4;
    const int q4   = q << 2;

    const int tr = tid >> 2;
    const int ts = tid & 3;

    f32x4 acc[4][4] = {};
    const int iters = K >> 5;

    auto stage = [&](int buf, int k) {
#pragma unroll
        for (int r = 0; r < 2; ++r) {
            const int row = r * 64 + tr;
            const int sw  = ts ^ ((row >> 1) & 3);
            gl_lds16(Ab + (size_t)(row0 + row) * K + k + sw * 8,
                     &sA[buf][0][0] + (size_t)(r * 256 + tid) * 8);
            gl_lds16(Wb + (size_t)(col0 + row) * K + k + sw * 8,
                     &sB[buf][0][0] + (size_t)(r * 256 + tid) * 8);
        }
    };

    stage(0, 0);

    for (int it = 0; it < iters; ++it) {
        __syncthreads();
        const int buf = it & 1;
        if (it + 1 < iters) stage(buf ^ 1, (it + 1) << 5);

        bf16x8 av[4], bv[4];
#pragma unroll
        for (int mi = 0; mi < 4; mi++) {
            const int row = wr * 64 + mi * 16 + lm;
            av[mi] = *(const bf16x8*)&sA[buf][row][(q ^ ((row >> 1) & 3)) * 8];
        }
#pragma unroll
        for (int ni = 0; ni < 4; ni++) {
            const int row = wc * 64 + ni * 16 + lm;
            bv[ni] = *(const bf16x8*)&sB[buf][row][(q ^ ((row >> 1) & 3)) * 8];
        }
#pragma unroll
        for (int mi = 0; mi < 4; mi++)
#pragma unroll
            for (int ni = 0; ni < 4; ni++)
                acc[mi][ni] = __builtin_amdgcn_mfma_f32_16x16x32_bf16(
                    av[mi], bv[ni], acc[mi][ni], 0, 0, 0);
    }

#pragma unroll
    for (int ni = 0; ni < 4; ni++) {
        const int col = col0 + wc * 64 + ni * 16 + lm;
        const float bsv = bias[col];
#pragma unroll
        for (int mi = 0; mi < 4; mi++) {
            const int rowb = row0 + wr * 64 + mi * 16 + q4;
#pragma unroll
            for (int rr = 0; rr < 4; rr++) {
                float v = acc[mi][ni][rr] + bsv;
                if (relu) v = fmaxf(v, 0.f);
                if (outbf16)
                    ((unsigned short*)Cv)[(size_t)(rowb + rr) * N + col] = f2bf(v);
                else
                    ((float*)Cv)[(size_t)(rowb + rr) * N + col] = v;
            }
        }
    }
}

__global__ __launch_bounds__(256) void gemm_std128(
    const unsigned short* __restrict__ Ab,
    const unsigned short* __restrict__ Wb, const float* __restrict__ bias,
    void* __restrict__ Cv, int outbf16, int relu, int N, int K)
{
    __shared__ unsigned short sA[2][128][32];
    __shared__ unsigned short sB[2][128][32];
    const int nwg = gridDim.x * gridDim.y;
    const int w = xcd_swz(blockIdx.x + gridDim.x * blockIdx.y, nwg);
    const int x = w % gridDim.x, y = w / gridDim.x;
    gemm_core128(Ab, Wb, bias, Cv, outbf16, relu,
                 y * 128, x * 128, N, K, sA, sB);
}

// fused: qk = qB@Wqk^T (N=512, x=0..3), v = tgtB@Wv^T (x=4..5),
// value = srcB@Wval^T over 43520 rows (x=6..7). grid (8, 340).
__global__ __launch_bounds__(256) void gemm_qkvval(
    const unsigned short* __restrict__ qB, const unsigned short* __restrict__ tgtB,
    const unsigned short* __restrict__ srcB,
    const unsigned short* __restrict__ Wsa, const float* __restrict__ bsa,
    unsigned short* __restrict__ qkB, unsigned short* __restrict__ vB,
    const unsigned short* __restrict__ Wval, const float* __restrict__ bval,
    unsigned short* __restrict__ valB)
{
    __shared__ unsigned short sA[2][128][32];
    __shared__ unsigned short sB[2][128][32];
    const int w = xcd_swz(blockIdx.x + 8 * blockIdx.y, 2720);
    const int x = w & 7, y = w >> 3;
    if (x < 4) {
        if (y >= 300) return;
        gemm_core128(qB, Wsa, bsa, qkB, 1, 0, y * 128, x * 128, 512, 256, sA, sB);
    } else if (x < 6) {
        if (y >= 300) return;
        gemm_core128(tgtB, Wsa + 512 * 256, bsa + 512, vB, 1, 0,
                     y * 128, (x - 4) * 128, 256, 256, sA, sB);
    } else {
        gemm_core128(srcB, Wval, bval, valB, 1, 0,
                     y * 128, (x - 6) * 128, 256, 256, sA, sB);
    }
}

// fused: off (N=256, x=0..1, bf16 out) and attw logits (N=128, x=2, fp32 out)
__global__ __launch_bounds__(256) void gemm_offaw(
    const unsigned short* __restrict__ X,
    const unsigned short* __restrict__ Woff, const float* __restrict__ boff,
    unsigned short* __restrict__ offB,
    const unsigned short* __restrict__ Watt, const float* __restrict__ batt,
    float* __restrict__ awL)
{
    __shared__ unsigned short sA[2][128][32];
    __shared__ unsigned short sB[2][128][32];
    const int w = xcd_swz(blockIdx.x + 3 * blockIdx.y, 900);
    const int x = w % 3, y = w / 3;
    if (x >= 2)
        gemm_core128(X, Watt, batt, awL, 0, 0,
                     y * 128, 0, 128, 256, sA, sB);
    else
        gemm_core128(X, Woff, boff, offB, 1, 0,
                     y * 128, x * 128, 256, 256, sA, sB);
}

// ---------------------------------------------------------------------------
// Self-attention over NC=16 groups; bf16 LDS, padded rows (conflict-free).
// ---------------------------------------------------------------------------
__global__ __launch_bounds__(256) void attn16(
    const unsigned short* __restrict__ QK, const unsigned short* __restrict__ V,
    unsigned short* __restrict__ O)
{
    __shared__ unsigned short sqk[16][520];
    __shared__ unsigned short sv[16][264];
    __shared__ float sp[128][17];

    const int g = blockIdx.x;
    const int tid = threadIdx.x;

    const uint4* qg = (const uint4*)(QK + (size_t)g * 8192);
    for (int i = tid; i < 1024; i += 256)
        *(uint4*)&sqk[i >> 6][(i & 63) * 8] = qg[i];
    const uint4* vg = (const uint4*)(V + (size_t)g * 4096);
    for (int i = tid; i < 512; i += 256)
        *(uint4*)&sv[i >> 5][(i & 31) * 8] = vg[i];
    __syncthreads();

#pragma unroll 2
    for (int s = tid; s < 2048; s += 256) {
        const int h = s >> 8, qi = (s >> 4) & 15, kj = s & 15;
        const uint4* qp = (const uint4*)&sqk[qi][h * 32];
        const uint4* kp = (const uint4*)&sqk[kj][256 + h * 32];
        float acc = 0.f;
#pragma unroll
        for (int c = 0; c < 4; c++) {
            uint4 qu = qp[c];
            uint4 ku = kp[c];
            acc += bf_lo(qu.x) * bf_lo(ku.x) + bf_hi(qu.x) * bf_hi(ku.x)
                 + bf_lo(qu.y) * bf_lo(ku.y) + bf_hi(qu.y) * bf_hi(ku.y)
                 + bf_lo(qu.z) * bf_lo(ku.z) + bf_hi(qu.z) * bf_hi(ku.z)
                 + bf_lo(qu.w) * bf_lo(ku.w) + bf_hi(qu.w) * bf_hi(ku.w);
        }
        sp[s >> 4][s & 15] = acc * 0.17677669529663687f;
    }
    __syncthreads();

    if (tid < 128) {
        float* row = sp[tid];
        float mx = row[0];
#pragma unroll
        for (int j = 1; j < 16; j++) mx = fmaxf(mx, row[j]);
        float sum = 0.f;
#pragma unroll
        for (int j = 0; j < 16; j++) { float e = __expf(row[j] - mx); row[j] = e; sum += e; }
        float inv = 1.f / sum;
#pragma unroll
        for (int j = 0; j < 16; j++) row[j] *= inv;
    }
    __syncthreads();

    uint2* og = (uint2*)(O + (size_t)g * 4096);
    for (int o = tid; o < 1024; o += 256) {
        const int qi = o >> 6, cq = o & 63, h = cq >> 3;
        const float* pr = sp[h * 16 + qi];
        float a0 = 0.f, a1 = 0.f, a2 = 0.f, a3 = 0.f;
#pragma unroll
        for (int j = 0; j < 16; j++) {
            uint2 u = *(const uint2*)&sv[j][cq * 4];
            float p = pr[j];
            a0 += p * bf_lo(u.x); a1 += p * bf_hi(u.x);
            a2 += p * bf_lo(u.y); a3 += p * bf_hi(u.y);
        }
        uint2 r; r.x = pk_bf16(a0, a1); r.y = pk_bf16(a2, a3);
        og[o] = r;
    }
}

// ---------------------------------------------------------------------------
// Residual + LN, wave-per-row (4 rows/block), butterfly shuffles, no LDS.
// ---------------------------------------------------------------------------
template <int XBF16, int WRITE2, int ADDQ>
__global__ __launch_bounds__(256) void ln_res4(
    const void* __restrict__ Xv, const float* __restrict__ R,
    const float* __restrict__ w, const float* __restrict__ b,
    float* __restrict__ out, unsigned short* __restrict__ out2,
    const float* __restrict__ qpos)
{
    const int row = blockIdx.x * 4 + (threadIdx.x >> 6);
    const int lane = threadIdx.x & 63;
    const size_t base = (size_t)row * 256 + lane * 4;

    float x0, x1, x2, x3;
    if (XBF16) {
        uint2 u = *(const uint2*)((const unsigned short*)Xv + base);
        x0 = bf_lo(u.x); x1 = bf_hi(u.x); x2 = bf_lo(u.y); x3 = bf_hi(u.y);
    } else {
        float4 f = *(const float4*)((const float*)Xv + base);
        x0 = f.x; x1 = f.y; x2 = f.z; x3 = f.w;
    }
    float4 r4 = *(const float4*)&R[base];
    float v0 = x0 + r4.x, v1 = x1 + r4.y, v2 = x2 + r4.z, v3 = x3 + r4.w;

    float s = v0 + v1 + v2 + v3;
#pragma unroll
    for (int o = 32; o > 0; o >>= 1) s += __shfl_xor(s, o);
    const float mean = s * (1.f / 256.f);
    const float d0 = v0 - mean, d1 = v1 - mean, d2 = v2 - mean, d3 = v3 - mean;
    float qv = d0 * d0 + d1 * d1 + d2 * d2 + d3 * d3;
#pragma unroll
    for (int o = 32; o > 0; o >>= 1) qv += __shfl_xor(qv, o);
    const float rs = rsqrtf(qv * (1.f / 256.f) + 1e-5f);

    float4 w4 = *(const float4*)&w[lane * 4];
    float4 b4 = *(const float4*)&b[lane * 4];
    float y0 = d0 * rs * w4.x + b4.x;
    float y1 = d1 * rs * w4.y + b4.y;
    float y2 = d2 * rs * w4.z + b4.z;
    float y3 = d3 * rs * w4.w + b4.w;

    float4 o4; o4.x = y0; o4.y = y1; o4.z = y2; o4.w = y3;
    *(float4*)&out[base] = o4;
    if (WRITE2) {
        float z0 = y0, z1 = y1, z2 = y2, z3 = y3;
        if (ADDQ) {
            float4 qp4 = *(const float4*)&qpos[base];
            z0 += qp4.x; z1 += qp4.y; z2 += qp4.z; z3 += qp4.w;
        }
        uint2 u; u.x = pk_bf16(z0, z1); u.y = pk_bf16(z2, z3);
        *(uint2*)(out2 + base) = u;
    }
}

// ---------------------------------------------------------------------------
// MS-deformable sampling (R4-proven v3): 256 threads/block, 8 queries/block,
// 2 q/wave (32 lanes/query; lane owns a 16-B slice of one head). 4800 blocks
// -> XCD chunk = exactly one batch per XCD (2.79 MB value slice L2-resident).
// Plain gather loop (VGPR 40, occ ~50%, 73 µs) — software-pipelining attempts
// (R5, R8) blew VGPR to 244-256 and regressed; structural latency floor.
// ---------------------------------------------------------------------------
__global__ __launch_bounds__(256) void ms_sample3(
    const unsigned short* __restrict__ VAL, const unsigned short* __restrict__ OFF,
    const float* __restrict__ AWL, const float* __restrict__ REF,
    unsigned short* __restrict__ OUT)
{
    __shared__ char smem[24576];
    unsigned short* soff = (unsigned short*)smem;            // [8][256]   (A)
    float*          saw  = (float*)(smem + 4096);            // [8][128]   (A)
    float*          sref = (float*)(smem + 8192);            // [8][8]     (A)
    float*          swt  = (float*)smem;                     // [8][16][8][4]   (B)
    unsigned short* sidx = (unsigned short*)(smem + 16384);  // [8][16][8][4]   (B)

    const int wblk = xcd_swz(blockIdx.x, 4800);
    const int m0 = wblk * 8, tid = threadIdx.x;

    // --- phase 0: load offsets / logits / refs (region A) ---
    ((uint4*)soff)[tid]  = ((const uint4*)(OFF + (size_t)m0 * 256))[tid];
    ((float4*)saw)[tid]  = ((const float4*)(AWL + (size_t)m0 * 128))[tid];
    if (tid < 64) sref[tid] = REF[(size_t)m0 * 8 + tid];
    __syncthreads();

    // --- phase 1: softmax over 16 logits per (q,h): 64 rows, all threads ---
    {
        const int row = tid >> 2, part = tid & 3;     // row = q*8+h
        float4 lg = *(float4*)&saw[row * 16 + part * 4];
        float mx = fmaxf(fmaxf(lg.x, lg.y), fmaxf(lg.z, lg.w));
        mx = fmaxf(mx, __shfl_xor(mx, 1));
        mx = fmaxf(mx, __shfl_xor(mx, 2));
        float e0 = __expf(lg.x - mx), e1 = __expf(lg.y - mx);
        float e2 = __expf(lg.z - mx), e3 = __expf(lg.w - mx);
        float s = e0 + e1 + e2 + e3;
        s += __shfl_xor(s, 1);
        s += __shfl_xor(s, 2);
        const float inv = 1.f / s;
        float4 pr; pr.x = e0 * inv; pr.y = e1 * inv; pr.z = e2 * inv; pr.w = e3 * inv;
        *(float4*)&saw[row * 16 + part * 4] = pr;
    }
    __syncthreads();

    // --- phase 2: decode 1024 items (4/thread) into registers ---
    float4  w4r[4];
    ushort4 rr4[4];
#pragma unroll
    for (int k = 0; k < 4; k++) {
        const int c = tid + k * 256;
        const int qi = c >> 7, h = c & 7, j = (c >> 3) & 15;
        const int l = j >> 2, p = j & 3;
        const int Wl = 64 >> l;
        const int st = (l == 0) ? 0 : (l == 1) ? 4096 : (l == 2) ? 5120 : 5376;
        const float fS = (float)Wl;
        const unsigned short* ob = &soff[qi * 256 + h * 32 + l * 8 + p * 2];
        const float x = sref[qi * 8 + l * 2 + 0] * fS + bf1(ob[0]) - 0.5f;
        const float y = sref[qi * 8 + l * 2 + 1] * fS + bf1(ob[1]) - 0.5f;
        const float x0f = floorf(x), y0f = floorf(y);
        const float fx = x - x0f, fy = y - y0f;
        const int x0 = (int)x0f, y0 = (int)y0f;
        const int x1 = x0 + 1, y1 = y0 + 1;
        const float vx0 = (x0 >= 0 && x0 < Wl) ? 1.f : 0.f;
        const float vx1 = (x1 >= 0 && x1 < Wl) ? 1.f : 0.f;
        const float vy0 = (y0 >= 0 && y0 < Wl) ? 1.f : 0.f;
        const float vy1 = (y1 >= 0 && y1 < Wl) ? 1.f : 0.f;
        const int cx0 = min(max(x0, 0), Wl - 1);
        const int cx1 = min(max(x1, 0), Wl - 1);
        const int cy0 = min(max(y0, 0), Wl - 1);
        const int cy1 = min(max(y1, 0), Wl - 1);
        const float aw = saw[qi * 128 + h * 16 + j];
        w4r[k].x = (1.f - fx) * (1.f - fy) * vx0 * vy0 * aw;
        w4r[k].y = fx * (1.f - fy) * vx1 * vy0 * aw;
        w4r[k].z = (1.f - fx) * fy * vx0 * vy1 * aw;
        w4r[k].w = fx * fy * vx1 * vy1 * aw;
        rr4[k].x = (unsigned short)(st + cy0 * Wl + cx0);
        rr4[k].y = (unsigned short)(st + cy0 * Wl + cx1);
        rr4[k].z = (unsigned short)(st + cy1 * Wl + cx0);
        rr4[k].w = (unsigned short)(st + cy1 * Wl + cx1);
    }
    __syncthreads();   // region A dead; write region B

#pragma unroll
    for (int k = 0; k < 4; k++) {
        const int c = tid + k * 256;
        const int qi = c >> 7, h = c & 7, j = (c >> 3) & 15;
        *(float4*)&swt[((qi * 16 + j) * 8 + h) * 4]   = w4r[k];
        *(ushort4*)&sidx[((qi * 16 + j) * 8 + h) * 4] = rr4[k];
    }
    __syncthreads();

    // --- phase 3: gather + weighted accumulate (16 B / lane) ---
    const int qi = tid >> 5;                // query within block (2/wave)
    const int l31 = tid & 31;               // lane within query
    const int h = l31 >> 2;                 // head
    const unsigned loff = (unsigned)l31 * 16;
    const int m = m0 + qi;
    const char* vbase = (const char*)VAL + (size_t)(m0 / 4800) * 5440 * 512;

    f32x2 a0 = {0.f, 0.f}, a1 = {0.f, 0.f}, a2 = {0.f, 0.f}, a3 = {0.f, 0.f};
#pragma unroll 8
    for (int j = 0; j < 16; j++) {
        const float4  w  = *(const float4*)&swt[((qi * 16 + j) * 8 + h) * 4];
        const ushort4 rw = *(const ushort4*)&sidx[((qi * 16 + j) * 8 + h) * 4];
        const uint4 c0 = *(const uint4*)(vbase + (((unsigned)rw.x << 9) + loff));
        const uint4 c1 = *(const uint4*)(vbase + (((unsigned)rw.y << 9) + loff));
        const uint4 c2 = *(const uint4*)(vbase + (((unsigned)rw.z << 9) + loff));
        const uint4 c3 = *(const uint4*)(vbase + (((unsigned)rw.w << 9) + loff));
        a0 += w.x * bfpair(c0.x); a1 += w.x * bfpair(c0.y);
        a2 += w.x * bfpair(c0.z); a3 += w.x * bfpair(c0.w);
        a0 += w.y * bfpair(c1.x); a1 += w.y * bfpair(c1.y);
        a2 += w.y * bfpair(c1.z); a3 += w.y * bfpair(c1.w);
        a0 += w.z * bfpair(c2.x); a1 += w.z * bfpair(c2.y);
        a2 += w.z * bfpair(c2.z); a3 += w.z * bfpair(c2.w);
        a0 += w.w * bfpair(c3.x); a1 += w.w * bfpair(c3.y);
        a2 += w.w * bfpair(c3.z); a3 += w.w * bfpair(c3.w);
    }
    uint4 o;
    o.x = pk_bf16(a0.x, a0.y);
    o.y = pk_bf16(a1.x, a1.y);
    o.z = pk_bf16(a2.x, a2.y);
    o.w = pk_bf16(a3.x, a3.y);
    *(uint4*)(OUT + (size_t)m * 256 + l31 * 8) = o;
}

// ---------------------------------------------------------------------------
// Launch
// ---------------------------------------------------------------------------
extern "C" void kernel_launch(void* const* d_in, const int* in_sizes, int n_in,
                              void* d_out, int out_size, void* d_ws, size_t ws_size,
                              hipStream_t stream)
{
    const float* tgt        = (const float*)d_in[0];
    const float* qpos       = (const float*)d_in[1];
    const float* refp       = (const float*)d_in[2];
    const float* src        = (const float*)d_in[3];
    const float* sa_in_w    = (const float*)d_in[7];
    const float* sa_in_b    = (const float*)d_in[8];
    const float* sa_out_w   = (const float*)d_in[9];
    const float* sa_out_b   = (const float*)d_in[10];
    const float* norm2_w    = (const float*)d_in[11];
    const float* norm2_b    = (const float*)d_in[12];
    const float* ca_value_w = (const float*)d_in[13];
    const float* ca_value_b = (const float*)d_in[14];
    const float* ca_off_w   = (const float*)d_in[15];
    const float* ca_off_b   = (const float*)d_in[16];
    const float* ca_attw_w  = (const float*)d_in[17];
    const float* ca_attw_b  = (const float*)d_in[18];
    const float* ca_out_w   = (const float*)d_in[19];
    const float* ca_out_b   = (const float*)d_in[20];
    const float* norm1_w    = (const float*)d_in[21];
    const float* norm1_b    = (const float*)d_in[22];
    const float* lin1_w     = (const float*)d_in[23];
    const float* lin1_b     = (const float*)d_in[24];
    const float* lin2_w     = (const float*)d_in[25];
    const float* lin2_b     = (const float*)d_in[26];
    const float* norm3_w    = (const float*)d_in[27];
    const float* norm3_b    = (const float*)d_in[28];
    float* out = (float*)d_out;

    float* ws = (float*)d_ws;
    float* A  = ws;
    float* Bx = A  + 9830400;
    float* Cx = Bx + 4915200;
    float* Dx = Cx + 4915200;
    float* Ex = Dx + 4915200;
    float* Fx = Ex + 5570560;
    float* Gx = Fx + 19660800;

    unsigned short* qkB   = (unsigned short*)A;
    float*          t1    = A;
    float*          t2    = A;
    unsigned short* vB    = (unsigned short*)Bx;
    unsigned short* t1qB  = (unsigned short*)Bx;
    unsigned short* sampB = (unsigned short*)Bx;
    unsigned short* l2B   = (unsigned short*)Bx;
    unsigned short* aoB   = (unsigned short*)Cx;
    unsigned short* offB  = (unsigned short*)Cx;
    unsigned short* coB   = (unsigned short*)Cx;
    unsigned short* t2B   = (unsigned short*)Cx;
    unsigned short* soB   = (unsigned short*)Dx;
    float*          awL   = Dx;
    unsigned short* valB  = (unsigned short*)Ex;
    unsigned short* hidB  = (unsigned short*)Fx;
    unsigned short* wG    = (unsigned short*)Gx;

    // bf16 activation staging lives in Fx (dead before hidB is written at FFN1)
    unsigned short* qBa   = (unsigned short*)Fx;
    unsigned short* tgtBa = qBa + 9830400;
    unsigned short* srcBa = tgtBa + 9830400;

    unsigned short* wSAIN  = wG;            // 768*256
    unsigned short* wSAOUT = wG + 196608;   // 256*256
    unsigned short* wVAL   = wG + 262144;   // 256*256
    unsigned short* wOFF   = wG + 327680;   // 256*256
    unsigned short* wATT   = wG + 393216;   // 128*256
    unsigned short* wCAOUT = wG + 425984;   // 256*256
    unsigned short* wL1    = wG + 491520;   // 1024*256
    unsigned short* wL2    = wG + 753664;   // 256*1024

    dim3 blk(256);

    CvtArgs ca;
    ca.wsrc[0] = sa_in_w;    ca.wdst[0] = wSAIN;  ca.n4[0] = 196608 / 4;
    ca.wsrc[1] = sa_out_w;   ca.wdst[1] = wSAOUT; ca.n4[1] = 65536 / 4;
    ca.wsrc[2] = ca_value_w; ca.wdst[2] = wVAL;   ca.n4[2] = 65536 / 4;
    ca.wsrc[3] = ca_off_w;   ca.wdst[3] = wOFF;   ca.n4[3] = 65536 / 4;
    ca.wsrc[4] = ca_attw_w;  ca.wdst[4] = wATT;   ca.n4[4] = 32768 / 4;
    ca.wsrc[5] = ca_out_w;   ca.wdst[5] = wCAOUT; ca.n4[5] = 65536 / 4;
    ca.wsrc[6] = lin1_w;     ca.wdst[6] = wL1;    ca.n4[6] = 262144 / 4;
    ca.wsrc[7] = lin2_w;     ca.wdst[7] = wL2;    ca.n4[7] = 262144 / 4;
    ca.tgt = tgt; ca.qpos = qpos; ca.src = src;
    ca.tgtB = tgtBa; ca.qB = qBa; ca.srcB = srcBa;
    cvt_all<<<2048, blk, 0, stream>>>(ca);

    // --- self-attention (+ value GEMM fused in) ---
    gemm_qkvval<<<dim3(8, 340), blk, 0, stream>>>(qBa, tgtBa, srcBa, wSAIN, sa_in_b,
                                                  qkB, vB, wVAL, ca_value_b, valB);
    attn16<<<2400, blk, 0, stream>>>(qkB, vB, aoB);
    gemm_std128<<<dim3(2, 300), blk, 0, stream>>>(aoB, wSAOUT, sa_out_b, soB, 1, 0, 256, 256);
    ln_res4<1, 1, 1><<<9600, blk, 0, stream>>>(soB, tgt, norm2_w, norm2_b, t1, t1qB, qpos);

    // --- MS deformable cross-attention ---
    gemm_offaw<<<dim3(3, 300), blk, 0, stream>>>(t1qB, wOFF, ca_off_b, offB, wATT, ca_attw_b, awL);
    ms_sample3<<<4800, blk, 0, stream>>>(valB, offB, awL, refp, sampB);
    gemm_std128<<<dim3(2, 300), blk, 0, stream>>>(sampB, wCAOUT, ca_out_b, coB, 1, 0, 256, 256);
    ln_res4<1, 1, 0><<<9600, blk, 0, stream>>>(coB, t1, norm1_w, norm1_b, t2, t2B, nullptr);

    // --- FFN ---
    gemm_std128<<<dim3(8, 300), blk, 0, stream>>>(t2B, wL1, lin1_b, hidB, 1, 1, 1024, 256);
    gemm_std128<<<dim3(2, 300), blk, 0, stream>>>(hidB, wL2, lin2_b, l2B, 1, 0, 256, 1024);
    ln_res4<1, 0, 0><<<9600, blk, 0, stream>>>(l2B, t2, norm3_w, norm3_b, out, nullptr, nullptr);
}

// Round 16
// 535.981 us; speedup vs baseline: 1.2355x; 1.0016x over previous
//
#include <hip/hip_runtime.h>

// ---------------------------------------------------------------------------
// D=256 HEADS=8 DH=32 LEVELS=4 POINTS=4 DFFN=1024 B=8 NQ=300 NC=16
// M1 = 38400, LEN_IN = 5440, value rows = 43520
// SPATIAL = (64,64),(32,32),(16,16),(8,8); level starts 0,4096,5120,5376
// ---------------------------------------------------------------------------

typedef __bf16 bf16x8 __attribute__((ext_vector_type(8)));
typedef float  f32x4  __attribute__((ext_vector_type(4)));
typedef float  f32x2  __attribute__((ext_vector_type(2)));

__device__ __forceinline__ unsigned pk_bf16(float lo, float hi)
{
    unsigned a = __float_as_uint(lo) + 0x8000u;
    unsigned b = __float_as_uint(hi) + 0x8000u;
    return __builtin_amdgcn_perm(b, a, 0x07060302u);
}
__device__ __forceinline__ unsigned short f2bf(float v)
{
    return (unsigned short)((__float_as_uint(v) + 0x8000u) >> 16);
}
__device__ __forceinline__ float bf_lo(unsigned u) { return __uint_as_float(u << 16); }
__device__ __forceinline__ float bf_hi(unsigned u) { return __uint_as_float(u & 0xffff0000u); }
__device__ __forceinline__ float bf1(unsigned short u) { return __uint_as_float((unsigned)u << 16); }
__device__ __forceinline__ f32x2 bfpair(unsigned u)
{
    f32x2 r;
    r.x = __uint_as_float(u << 16);
    r.y = __uint_as_float(u & 0xffff0000u);
    return r;
}

// XCD-aware chunked block swizzle (bijective for any nwg; m204 variant).
__device__ __forceinline__ int xcd_swz(int wgid, int nwg)
{
    const int q = nwg >> 3, r = nwg & 7;
    const int x = wgid & 7, k = wgid >> 3;
    return (x < r ? x * (q + 1) : r * (q + 1) + (x - r) * q) + k;
}

// async global->LDS, 16 B per lane. LDS dest must be wave-uniform base + lane*16.
__device__ __forceinline__ void gl_lds16(const unsigned short* g, unsigned short* l)
{
    __builtin_amdgcn_global_load_lds(
        (const __attribute__((address_space(1))) unsigned int*)g,
        (__attribute__((address_space(3))) unsigned int*)l,
        16, 0, 0);
}

// ---------------------------------------------------------------------------
// Combined pre-conversion (one dispatch): weights fp32->bf16 (8 segments) +
// activations tgtB = bf16(tgt), qB = bf16(tgt+qpos), srcB = bf16(src).
// ---------------------------------------------------------------------------
struct CvtArgs {
    const float* wsrc[8];
    unsigned short* wdst[8];
    int n4[8];
    const float* tgt;
    const float* qpos;
    const float* src;
    unsigned short* tgtB;
    unsigned short* qB;
    unsigned short* srcB;
};

__global__ __launch_bounds__(256) void cvt_all(CvtArgs a)
{
    const int gid = blockIdx.x * 256 + threadIdx.x;
    const int stride = gridDim.x * 256;

    for (int i = gid; i < 2457600; i += stride) {          // 38400*256/4
        float4 t = ((const float4*)a.tgt)[i];
        float4 p = ((const float4*)a.qpos)[i];
        uint2 o1; o1.x = pk_bf16(t.x, t.y); o1.y = pk_bf16(t.z, t.w);
        ((uint2*)a.tgtB)[i] = o1;
        uint2 o2; o2.x = pk_bf16(t.x + p.x, t.y + p.y);
        o2.y = pk_bf16(t.z + p.z, t.w + p.w);
        ((uint2*)a.qB)[i] = o2;
    }
    for (int i = gid; i < 2785280; i += stride) {          // 8*5440*256/4
        float4 s = ((const float4*)a.src)[i];
        uint2 c; c.x = pk_bf16(s.x, s.y); c.y = pk_bf16(s.z, s.w);
        ((uint2*)a.srcB)[i] = c;
    }
#pragma unroll
    for (int s = 0; s < 8; s++) {
        const float4* sp = (const float4*)a.wsrc[s];
        uint2* dp = (uint2*)a.wdst[s];
        for (int i = gid; i < a.n4[s]; i += stride) {
            float4 f = sp[i];
            uint2 o; o.x = pk_bf16(f.x, f.y); o.y = pk_bf16(f.z, f.w);
            dp[i] = o;
        }
    }
}

// ---------------------------------------------------------------------------
// GEMM core (m97 structure): 128x128 tile, BK=32, double-buffered LDS,
// global_load_lds width=16 staging, one barrier per K-step. 4 waves (2x2).
// Both-sides XOR slot-swizzle (slot ^= (row>>1)&3).
// A is bf16 [M,K]; W is bf16 [N,K]; C row-major [M,N].
// ---------------------------------------------------------------------------
__device__ __forceinline__ void gemm_core128(
    const unsigned short* __restrict__ Ab,
    const unsigned short* __restrict__ Wb, const float* __restrict__ bias,
    void* __restrict__ Cv, int outbf16, int relu,
    int row0, int col0, int N, int K,
    unsigned short (*sA)[128][32], unsigned short (*sB)[128][32])
{
    const int tid  = threadIdx.x;
    const int lane = tid & 63;
    const int wv   = tid >> 6;
    const int wr   = wv >> 1;
    const int wc   = wv & 1;
    const int lm   = lane & 15;
    const int q    = lane >> 4;
    const int q4   = q << 2;

    const int tr = tid >> 2;
    const int ts = tid & 3;

    f32x4 acc[4][4] = {};
    const int iters = K >> 5;

    auto stage = [&](int buf, int k) {
#pragma unroll
        for (int r = 0; r < 2; ++r) {
            const int row = r * 64 + tr;
            const int sw  = ts ^ ((row >> 1) & 3);
            gl_lds16(Ab + (size_t)(row0 + row) * K + k + sw * 8,
                     &sA[buf][0][0] + (size_t)(r * 256 + tid) * 8);
            gl_lds16(Wb + (size_t)(col0 + row) * K + k + sw * 8,
                     &sB[buf][0][0] + (size_t)(r * 256 + tid) * 8);
        }
    };

    stage(0, 0);

    for (int it = 0; it < iters; ++it) {
        __syncthreads();
        const int buf = it & 1;
        if (it + 1 < iters) stage(buf ^ 1, (it + 1) << 5);

        bf16x8 av[4], bv[4];
#pragma unroll
        for (int mi = 0; mi < 4; mi++) {
            const int row = wr * 64 + mi * 16 + lm;
            av[mi] = *(const bf16x8*)&sA[buf][row][(q ^ ((row >> 1) & 3)) * 8];
        }
#pragma unroll
        for (int ni = 0; ni < 4; ni++) {
            const int row = wc * 64 + ni * 16 + lm;
            bv[ni] = *(const bf16x8*)&sB[buf][row][(q ^ ((row >> 1) & 3)) * 8];
        }
#pragma unroll
        for (int mi = 0; mi < 4; mi++)
#pragma unroll
            for (int ni = 0; ni < 4; ni++)
                acc[mi][ni] = __builtin_amdgcn_mfma_f32_16x16x32_bf16(
                    av[mi], bv[ni], acc[mi][ni], 0, 0, 0);
    }

#pragma unroll
    for (int ni = 0; ni < 4; ni++) {
        const int col = col0 + wc * 64 + ni * 16 + lm;
        const float bsv = bias[col];
#pragma unroll
        for (int mi = 0; mi < 4; mi++) {
            const int rowb = row0 + wr * 64 + mi * 16 + q4;
#pragma unroll
            for (int rr = 0; rr < 4; rr++) {
                float v = acc[mi][ni][rr] + bsv;
                if (relu) v = fmaxf(v, 0.f);
                if (outbf16)
                    ((unsigned short*)Cv)[(size_t)(rowb + rr) * N + col] = f2bf(v);
                else
                    ((float*)Cv)[(size_t)(rowb + rr) * N + col] = v;
            }
        }
    }
}

__global__ __launch_bounds__(256) void gemm_std128(
    const unsigned short* __restrict__ Ab,
    const unsigned short* __restrict__ Wb, const float* __restrict__ bias,
    void* __restrict__ Cv, int outbf16, int relu, int N, int K)
{
    __shared__ unsigned short sA[2][128][32];
    __shared__ unsigned short sB[2][128][32];
    const int nwg = gridDim.x * gridDim.y;
    const int w = xcd_swz(blockIdx.x + gridDim.x * blockIdx.y, nwg);
    const int x = w % gridDim.x, y = w / gridDim.x;
    gemm_core128(Ab, Wb, bias, Cv, outbf16, relu,
                 y * 128, x * 128, N, K, sA, sB);
}

// fused: qk = qB@Wqk^T (N=512, x=0..3), v = tgtB@Wv^T (x=4..5),
// value = srcB@Wval^T over 43520 rows (x=6..7). grid (8, 340).
__global__ __launch_bounds__(256) void gemm_qkvval(
    const unsigned short* __restrict__ qB, const unsigned short* __restrict__ tgtB,
    const unsigned short* __restrict__ srcB,
    const unsigned short* __restrict__ Wsa, const float* __restrict__ bsa,
    unsigned short* __restrict__ qkB, unsigned short* __restrict__ vB,
    const unsigned short* __restrict__ Wval, const float* __restrict__ bval,
    unsigned short* __restrict__ valB)
{
    __shared__ unsigned short sA[2][128][32];
    __shared__ unsigned short sB[2][128][32];
    const int w = xcd_swz(blockIdx.x + 8 * blockIdx.y, 2720);
    const int x = w & 7, y = w >> 3;
    if (x < 4) {
        if (y >= 300) return;
        gemm_core128(qB, Wsa, bsa, qkB, 1, 0, y * 128, x * 128, 512, 256, sA, sB);
    } else if (x < 6) {
        if (y >= 300) return;
        gemm_core128(tgtB, Wsa + 512 * 256, bsa + 512, vB, 1, 0,
                     y * 128, (x - 4) * 128, 256, 256, sA, sB);
    } else {
        gemm_core128(srcB, Wval, bval, valB, 1, 0,
                     y * 128, (x - 6) * 128, 256, 256, sA, sB);
    }
}

// fused: off (N=256, x=0..1, bf16 out) and attw logits (N=128, x=2, fp32 out)
__global__ __launch_bounds__(256) void gemm_offaw(
    const unsigned short* __restrict__ X,
    const unsigned short* __restrict__ Woff, const float* __restrict__ boff,
    unsigned short* __restrict__ offB,
    const unsigned short* __restrict__ Watt, const float* __restrict__ batt,
    float* __restrict__ awL)
{
    __shared__ unsigned short sA[2][128][32];
    __shared__ unsigned short sB[2][128][32];
    const int w = xcd_swz(blockIdx.x + 3 * blockIdx.y, 900);
    const int x = w % 3, y = w / 3;
    if (x >= 2)
        gemm_core128(X, Watt, batt, awL, 0, 0,
                     y * 128, 0, 128, 256, sA, sB);
    else
        gemm_core128(X, Woff, boff, offB, 1, 0,
                     y * 128, x * 128, 256, 256, sA, sB);
}

// ---------------------------------------------------------------------------
// Self-attention over NC=16 groups; bf16 LDS, padded rows (conflict-free).
// ---------------------------------------------------------------------------
__global__ __launch_bounds__(256) void attn16(
    const unsigned short* __restrict__ QK, const unsigned short* __restrict__ V,
    unsigned short* __restrict__ O)
{
    __shared__ unsigned short sqk[16][520];
    __shared__ unsigned short sv[16][264];
    __shared__ float sp[128][17];

    const int g = blockIdx.x;
    const int tid = threadIdx.x;

    const uint4* qg = (const uint4*)(QK + (size_t)g * 8192);
    for (int i = tid; i < 1024; i += 256)
        *(uint4*)&sqk[i >> 6][(i & 63) * 8] = qg[i];
    const uint4* vg = (const uint4*)(V + (size_t)g * 4096);
    for (int i = tid; i < 512; i += 256)
        *(uint4*)&sv[i >> 5][(i & 31) * 8] = vg[i];
    __syncthreads();

#pragma unroll 2
    for (int s = tid; s < 2048; s += 256) {
        const int h = s >> 8, qi = (s >> 4) & 15, kj = s & 15;
        const uint4* qp = (const uint4*)&sqk[qi][h * 32];
        const uint4* kp = (const uint4*)&sqk[kj][256 + h * 32];
        float acc = 0.f;
#pragma unroll
        for (int c = 0; c < 4; c++) {
            uint4 qu = qp[c];
            uint4 ku = kp[c];
            acc += bf_lo(qu.x) * bf_lo(ku.x) + bf_hi(qu.x) * bf_hi(ku.x)
                 + bf_lo(qu.y) * bf_lo(ku.y) + bf_hi(qu.y) * bf_hi(ku.y)
                 + bf_lo(qu.z) * bf_lo(ku.z) + bf_hi(qu.z) * bf_hi(ku.z)
                 + bf_lo(qu.w) * bf_lo(ku.w) + bf_hi(qu.w) * bf_hi(ku.w);
        }
        sp[s >> 4][s & 15] = acc * 0.17677669529663687f;
    }
    __syncthreads();

    if (tid < 128) {
        float* row = sp[tid];
        float mx = row[0];
#pragma unroll
        for (int j = 1; j < 16; j++) mx = fmaxf(mx, row[j]);
        float sum = 0.f;
#pragma unroll
        for (int j = 0; j < 16; j++) { float e = __expf(row[j] - mx); row[j] = e; sum += e; }
        float inv = 1.f / sum;
#pragma unroll
        for (int j = 0; j < 16; j++) row[j] *= inv;
    }
    __syncthreads();

    uint2* og = (uint2*)(O + (size_t)g * 4096);
    for (int o = tid; o < 1024; o += 256) {
        const int qi = o >> 6, cq = o & 63, h = cq >> 3;
        const float* pr = sp[h * 16 + qi];
        float a0 = 0.f, a1 = 0.f, a2 = 0.f, a3 = 0.f;
#pragma unroll
        for (int j = 0; j < 16; j++) {
            uint2 u = *(const uint2*)&sv[j][cq * 4];
            float p = pr[j];
            a0 += p * bf_lo(u.x); a1 += p * bf_hi(u.x);
            a2 += p * bf_lo(u.y); a3 += p * bf_hi(u.y);
        }
        uint2 r; r.x = pk_bf16(a0, a1); r.y = pk_bf16(a2, a3);
        og[o] = r;
    }
}

// ---------------------------------------------------------------------------
// Residual + LN, wave-per-row (4 rows/block), butterfly shuffles, no LDS.
// ---------------------------------------------------------------------------
template <int XBF16, int WRITE2, int ADDQ>
__global__ __launch_bounds__(256) void ln_res4(
    const void* __restrict__ Xv, const float* __restrict__ R,
    const float* __restrict__ w, const float* __restrict__ b,
    float* __restrict__ out, unsigned short* __restrict__ out2,
    const float* __restrict__ qpos)
{
    const int row = blockIdx.x * 4 + (threadIdx.x >> 6);
    const int lane = threadIdx.x & 63;
    const size_t base = (size_t)row * 256 + lane * 4;

    float x0, x1, x2, x3;
    if (XBF16) {
        uint2 u = *(const uint2*)((const unsigned short*)Xv + base);
        x0 = bf_lo(u.x); x1 = bf_hi(u.x); x2 = bf_lo(u.y); x3 = bf_hi(u.y);
    } else {
        float4 f = *(const float4*)((const float*)Xv + base);
        x0 = f.x; x1 = f.y; x2 = f.z; x3 = f.w;
    }
    float4 r4 = *(const float4*)&R[base];
    float v0 = x0 + r4.x, v1 = x1 + r4.y, v2 = x2 + r4.z, v3 = x3 + r4.w;

    float s = v0 + v1 + v2 + v3;
#pragma unroll
    for (int o = 32; o > 0; o >>= 1) s += __shfl_xor(s, o);
    const float mean = s * (1.f / 256.f);
    const float d0 = v0 - mean, d1 = v1 - mean, d2 = v2 - mean, d3 = v3 - mean;
    float qv = d0 * d0 + d1 * d1 + d2 * d2 + d3 * d3;
#pragma unroll
    for (int o = 32; o > 0; o >>= 1) qv += __shfl_xor(qv, o);
    const float rs = rsqrtf(qv * (1.f / 256.f) + 1e-5f);

    float4 w4 = *(const float4*)&w[lane * 4];
    float4 b4 = *(const float4*)&b[lane * 4];
    float y0 = d0 * rs * w4.x + b4.x;
    float y1 = d1 * rs * w4.y + b4.y;
    float y2 = d2 * rs * w4.z + b4.z;
    float y3 = d3 * rs * w4.w + b4.w;

    float4 o4; o4.x = y0; o4.y = y1; o4.z = y2; o4.w = y3;
    *(float4*)&out[base] = o4;
    if (WRITE2) {
        float z0 = y0, z1 = y1, z2 = y2, z3 = y3;
        if (ADDQ) {
            float4 qp4 = *(const float4*)&qpos[base];
            z0 += qp4.x; z1 += qp4.y; z2 += qp4.z; z3 += qp4.w;
        }
        uint2 u; u.x = pk_bf16(z0, z1); u.y = pk_bf16(z2, z3);
        *(uint2*)(out2 + base) = u;
    }
}

// ---------------------------------------------------------------------------
// MS-deformable sampling v6: j-loop split across wave lane-halves.
// 256 thr/block, 4 queries/block (1 query/wave, 64 lanes): lanes 0-31 do
// j=0-7, lanes 32-63 do j=8-15 for the SAME (head,slice); partials combined
// with 8 __shfl_xor(.,32). Per-thread serial latency chain HALVED (8 vs 16
// dependent-load iterations) with unchanged per-thread VGPR (~40) — the TLP
// route to latency hiding after both register-pipelining attempts (R5/R8)
// blew regalloc. 9600 blocks -> XCD chunk (1200 blocks) = exactly one batch;
// LDS 12.4 KB (was 24.5).
// ---------------------------------------------------------------------------
__global__ __launch_bounds__(256) void ms_sample6(
    const unsigned short* __restrict__ VAL, const unsigned short* __restrict__ OFF,
    const float* __restrict__ AWL, const float* __restrict__ REF,
    unsigned short* __restrict__ OUT)
{
    __shared__ char smem[12416];
    unsigned short* soff = (unsigned short*)smem;            // [4][256]   (A)
    float*          saw  = (float*)(smem + 2048);            // [4][128]   (A)
    float*          sref = (float*)(smem + 12288);           // [4][8]     (A, disjoint from B)
    float*          swt  = (float*)smem;                     // [4][16][8][4] f32  (B)
    unsigned short* sidx = (unsigned short*)(smem + 8192);   // [4][16][8][4] u16  (B)

    const int wblk = xcd_swz(blockIdx.x, 9600);
    const int m0 = wblk * 4, tid = threadIdx.x;

    // --- phase 0: load offsets / logits / refs (region A) ---
    ((uint2*)soff)[tid]  = ((const uint2*)(OFF + (size_t)m0 * 256))[tid];
    ((float2*)saw)[tid]  = ((const float2*)(AWL + (size_t)m0 * 128))[tid];
    if (tid < 32) sref[tid] = REF[(size_t)m0 * 8 + tid];
    __syncthreads();

    // --- phase 1: softmax over 16 logits per (q,h): 32 rows, tid<128 ---
    if (tid < 128) {
        const int row = tid >> 2, part = tid & 3;     // row = q*8+h
        float4 lg = *(float4*)&saw[row * 16 + part * 4];
        float mx = fmaxf(fmaxf(lg.x, lg.y), fmaxf(lg.z, lg.w));
        mx = fmaxf(mx, __shfl_xor(mx, 1));
        mx = fmaxf(mx, __shfl_xor(mx, 2));
        float e0 = __expf(lg.x - mx), e1 = __expf(lg.y - mx);
        float e2 = __expf(lg.z - mx), e3 = __expf(lg.w - mx);
        float s = e0 + e1 + e2 + e3;
        s += __shfl_xor(s, 1);
        s += __shfl_xor(s, 2);
        const float inv = 1.f / s;
        float4 pr; pr.x = e0 * inv; pr.y = e1 * inv; pr.z = e2 * inv; pr.w = e3 * inv;
        *(float4*)&saw[row * 16 + part * 4] = pr;
    }
    __syncthreads();

    // --- phase 2: decode 512 items (2/thread) into registers ---
    float4  w4r[2];
    ushort4 rr4[2];
#pragma unroll
    for (int k = 0; k < 2; k++) {
        const int c = tid + k * 256;
        const int qi = c >> 7, h = c & 7, j = (c >> 3) & 15;
        const int l = j >> 2, p = j & 3;
        const int Wl = 64 >> l;
        const int st = (l == 0) ? 0 : (l == 1) ? 4096 : (l == 2) ? 5120 : 5376;
        const float fS = (float)Wl;
        const unsigned short* ob = &soff[qi * 256 + h * 32 + l * 8 + p * 2];
        const float x = sref[qi * 8 + l * 2 + 0] * fS + bf1(ob[0]) - 0.5f;
        const float y = sref[qi * 8 + l * 2 + 1] * fS + bf1(ob[1]) - 0.5f;
        const float x0f = floorf(x), y0f = floorf(y);
        const float fx = x - x0f, fy = y - y0f;
        const int x0 = (int)x0f, y0 = (int)y0f;
        const int x1 = x0 + 1, y1 = y0 + 1;
        const float vx0 = (x0 >= 0 && x0 < Wl) ? 1.f : 0.f;
        const float vx1 = (x1 >= 0 && x1 < Wl) ? 1.f : 0.f;
        const float vy0 = (y0 >= 0 && y0 < Wl) ? 1.f : 0.f;
        const float vy1 = (y1 >= 0 && y1 < Wl) ? 1.f : 0.f;
        const int cx0 = min(max(x0, 0), Wl - 1);
        const int cx1 = min(max(x1, 0), Wl - 1);
        const int cy0 = min(max(y0, 0), Wl - 1);
        const int cy1 = min(max(y1, 0), Wl - 1);
        const float aw = saw[qi * 128 + h * 16 + j];
        w4r[k].x = (1.f - fx) * (1.f - fy) * vx0 * vy0 * aw;
        w4r[k].y = fx * (1.f - fy) * vx1 * vy0 * aw;
        w4r[k].z = (1.f - fx) * fy * vx0 * vy1 * aw;
        w4r[k].w = fx * fy * vx1 * vy1 * aw;
        rr4[k].x = (unsigned short)(st + cy0 * Wl + cx0);
        rr4[k].y = (unsigned short)(st + cy0 * Wl + cx1);
        rr4[k].z = (unsigned short)(st + cy1 * Wl + cx0);
        rr4[k].w = (unsigned short)(st + cy1 * Wl + cx1);
    }
    __syncthreads();   // region A (soff/saw) dead; write region B

#pragma unroll
    for (int k = 0; k < 2; k++) {
        const int c = tid + k * 256;
        const int qi = c >> 7, h = c & 7, j = (c >> 3) & 15;
        *(float4*)&swt[((qi * 16 + j) * 8 + h) * 4]   = w4r[k];
        *(ushort4*)&sidx[((qi * 16 + j) * 8 + h) * 4] = rr4[k];
    }
    __syncthreads();

    // --- phase 3: gather + weighted accumulate; wave = query, lane-halves
    //     split the j range (0-7 | 8-15), 16 B / lane slice ---
    const int qi = tid >> 6;                // query within block (1/wave)
    const int lane = tid & 63;
    const int jh = lane >> 5;               // j-half: 0 -> j 0..7, 1 -> j 8..15
    const int l31 = lane & 31;              // data lane within query
    const int h = l31 >> 2;                 // head
    const unsigned loff = (unsigned)l31 * 16;
    const int m = m0 + qi;
    const char* vbase = (const char*)VAL + (size_t)(m0 / 4800) * 5440 * 512;
    const int j0 = jh * 8;

    f32x2 a0 = {0.f, 0.f}, a1 = {0.f, 0.f}, a2 = {0.f, 0.f}, a3 = {0.f, 0.f};
#pragma unroll 8
    for (int jj = 0; jj < 8; jj++) {
        const int j = j0 + jj;
        const float4  w  = *(const float4*)&swt[((qi * 16 + j) * 8 + h) * 4];
        const ushort4 rw = *(const ushort4*)&sidx[((qi * 16 + j) * 8 + h) * 4];
        const uint4 c0 = *(const uint4*)(vbase + (((unsigned)rw.x << 9) + loff));
        const uint4 c1 = *(const uint4*)(vbase + (((unsigned)rw.y << 9) + loff));
        const uint4 c2 = *(const uint4*)(vbase + (((unsigned)rw.z << 9) + loff));
        const uint4 c3 = *(const uint4*)(vbase + (((unsigned)rw.w << 9) + loff));
        a0 += w.x * bfpair(c0.x); a1 += w.x * bfpair(c0.y);
        a2 += w.x * bfpair(c0.z); a3 += w.x * bfpair(c0.w);
        a0 += w.y * bfpair(c1.x); a1 += w.y * bfpair(c1.y);
        a2 += w.y * bfpair(c1.z); a3 += w.y * bfpair(c1.w);
        a0 += w.z * bfpair(c2.x); a1 += w.z * bfpair(c2.y);
        a2 += w.z * bfpair(c2.z); a3 += w.z * bfpair(c2.w);
        a0 += w.w * bfpair(c3.x); a1 += w.w * bfpair(c3.y);
        a2 += w.w * bfpair(c3.z); a3 += w.w * bfpair(c3.w);
    }

    // combine j-halves: lane L and L+32 hold partials for the same slice
    a0.x += __shfl_xor(a0.x, 32); a0.y += __shfl_xor(a0.y, 32);
    a1.x += __shfl_xor(a1.x, 32); a1.y += __shfl_xor(a1.y, 32);
    a2.x += __shfl_xor(a2.x, 32); a2.y += __shfl_xor(a2.y, 32);
    a3.x += __shfl_xor(a3.x, 32); a3.y += __shfl_xor(a3.y, 32);

    if (jh == 0) {
        uint4 o;
        o.x = pk_bf16(a0.x, a0.y);
        o.y = pk_bf16(a1.x, a1.y);
        o.z = pk_bf16(a2.x, a2.y);
        o.w = pk_bf16(a3.x, a3.y);
        *(uint4*)(OUT + (size_t)m * 256 + l31 * 8) = o;
    }
}

// ---------------------------------------------------------------------------
// Launch
// ---------------------------------------------------------------------------
extern "C" void kernel_launch(void* const* d_in, const int* in_sizes, int n_in,
                              void* d_out, int out_size, void* d_ws, size_t ws_size,
                              hipStream_t stream)
{
    const float* tgt        = (const float*)d_in[0];
    const float* qpos       = (const float*)d_in[1];
    const float* refp       = (const float*)d_in[2];
    const float* src        = (const float*)d_in[3];
    const float* sa_in_w    = (const float*)d_in[7];
    const float* sa_in_b    = (const float*)d_in[8];
    const float* sa_out_w   = (const float*)d_in[9];
    const float* sa_out_b   = (const float*)d_in[10];
    const float* norm2_w    = (const float*)d_in[11];
    const float* norm2_b    = (const float*)d_in[12];
    const float* ca_value_w = (const float*)d_in[13];
    const float* ca_value_b = (const float*)d_in[14];
    const float* ca_off_w   = (const float*)d_in[15];
    const float* ca_off_b   = (const float*)d_in[16];
    const float* ca_attw_w  = (const float*)d_in[17];
    const float* ca_attw_b  = (const float*)d_in[18];
    const float* ca_out_w   = (const float*)d_in[19];
    const float* ca_out_b   = (const float*)d_in[20];
    const float* norm1_w    = (const float*)d_in[21];
    const float* norm1_b    = (const float*)d_in[22];
    const float* lin1_w     = (const float*)d_in[23];
    const float* lin1_b     = (const float*)d_in[24];
    const float* lin2_w     = (const float*)d_in[25];
    const float* lin2_b     = (const float*)d_in[26];
    const float* norm3_w    = (const float*)d_in[27];
    const float* norm3_b    = (const float*)d_in[28];
    float* out = (float*)d_out;

    float* ws = (float*)d_ws;
    float* A  = ws;
    float* Bx = A  + 9830400;
    float* Cx = Bx + 4915200;
    float* Dx = Cx + 4915200;
    float* Ex = Dx + 4915200;
    float* Fx = Ex + 5570560;
    float* Gx = Fx + 19660800;

    unsigned short* qkB   = (unsigned short*)A;
    float*          t1    = A;
    float*          t2    = A;
    unsigned short* vB    = (unsigned short*)Bx;
    unsigned short* t1qB  = (unsigned short*)Bx;
    unsigned short* sampB = (unsigned short*)Bx;
    unsigned short* l2B   = (unsigned short*)Bx;
    unsigned short* aoB   = (unsigned short*)Cx;
    unsigned short* offB  = (unsigned short*)Cx;
    unsigned short* coB   = (unsigned short*)Cx;
    unsigned short* t2B   = (unsigned short*)Cx;
    unsigned short* soB   = (unsigned short*)Dx;
    float*          awL   = Dx;
    unsigned short* valB  = (unsigned short*)Ex;
    unsigned short* hidB  = (unsigned short*)Fx;
    unsigned short* wG    = (unsigned short*)Gx;

    // bf16 activation staging lives in Fx (dead before hidB is written at FFN1)
    unsigned short* qBa   = (unsigned short*)Fx;
    unsigned short* tgtBa = qBa + 9830400;
    unsigned short* srcBa = tgtBa + 9830400;

    unsigned short* wSAIN  = wG;            // 768*256
    unsigned short* wSAOUT = wG + 196608;   // 256*256
    unsigned short* wVAL   = wG + 262144;   // 256*256
    unsigned short* wOFF   = wG + 327680;   // 256*256
    unsigned short* wATT   = wG + 393216;   // 128*256
    unsigned short* wCAOUT = wG + 425984;   // 256*256
    unsigned short* wL1    = wG + 491520;   // 1024*256
    unsigned short* wL2    = wG + 753664;   // 256*1024

    dim3 blk(256);

    CvtArgs ca;
    ca.wsrc[0] = sa_in_w;    ca.wdst[0] = wSAIN;  ca.n4[0] = 196608 / 4;
    ca.wsrc[1] = sa_out_w;   ca.wdst[1] = wSAOUT; ca.n4[1] = 65536 / 4;
    ca.wsrc[2] = ca_value_w; ca.wdst[2] = wVAL;   ca.n4[2] = 65536 / 4;
    ca.wsrc[3] = ca_off_w;   ca.wdst[3] = wOFF;   ca.n4[3] = 65536 / 4;
    ca.wsrc[4] = ca_attw_w;  ca.wdst[4] = wATT;   ca.n4[4] = 32768 / 4;
    ca.wsrc[5] = ca_out_w;   ca.wdst[5] = wCAOUT; ca.n4[5] = 65536 / 4;
    ca.wsrc[6] = lin1_w;     ca.wdst[6] = wL1;    ca.n4[6] = 262144 / 4;
    ca.wsrc[7] = lin2_w;     ca.wdst[7] = wL2;    ca.n4[7] = 262144 / 4;
    ca.tgt = tgt; ca.qpos = qpos; ca.src = src;
    ca.tgtB = tgtBa; ca.qB = qBa; ca.srcB = srcBa;
    cvt_all<<<2048, blk, 0, stream>>>(ca);

    // --- self-attention (+ value GEMM fused in) ---
    gemm_qkvval<<<dim3(8, 340), blk, 0, stream>>>(qBa, tgtBa, srcBa, wSAIN, sa_in_b,
                                                  qkB, vB, wVAL, ca_value_b, valB);
    attn16<<<2400, blk, 0, stream>>>(qkB, vB, aoB);
    gemm_std128<<<dim3(2, 300), blk, 0, stream>>>(aoB, wSAOUT, sa_out_b, soB, 1, 0, 256, 256);
    ln_res4<1, 1, 1><<<9600, blk, 0, stream>>>(soB, tgt, norm2_w, norm2_b, t1, t1qB, qpos);

    // --- MS deformable cross-attention ---
    gemm_offaw<<<dim3(3, 300), blk, 0, stream>>>(t1qB, wOFF, ca_off_b, offB, wATT, ca_attw_b, awL);
    ms_sample6<<<9600, blk, 0, stream>>>(valB, offB, awL, refp, sampB);
    gemm_std128<<<dim3(2, 300), blk, 0, stream>>>(sampB, wCAOUT, ca_out_b, coB, 1, 0, 256, 256);
    ln_res4<1, 1, 0><<<9600, blk, 0, stream>>>(coB, t1, norm1_w, norm1_b, t2, t2B, nullptr);

    // --- FFN ---
    gemm_std128<<<dim3(8, 300), blk, 0, stream>>>(t2B, wL1, lin1_b, hidB, 1, 1, 1024, 256);
    gemm_std128<<<dim3(2, 300), blk, 0, stream>>>(hidB, wL2, lin2_b, l2B, 1, 0, 256, 1024);
    ln_res4<1, 0, 0><<<9600, blk, 0, stream>>>(l2B, t2, norm3_w, norm3_b, out, nullptr, nullptr);
}